// Round 7
// baseline (1794.139 us; speedup 1.0000x reference)
//
#include <hip/hip_runtime.h>
#include <math.h>

#define NB 128
#define VS 10475
#define VF 5023
#define VM 778
#define NS3v (VS*3)   // 31425
#define NF3v (VF*3)   // 15069
#define NM3v (VM*3)   // 2334
#define KSH 350
#define KPF 36
#define KPM 135
#define KPS 486
#define NHD 3000

__device__ const int PAR_F[5]  = {-1,0,1,1,1};
__device__ const int PAR_M[16] = {-1,0,1,2,0,4,5,0,7,8,0,10,11,0,13,14};
__device__ const int PAR_S[55] = {-1,0,0,0,1,2,3,4,5,6,7,8,9,9,9,12,13,14,16,17,18,19,15,15,15,
                                  20,25,26,20,28,29,20,31,32,20,34,35,20,37,38,21,40,41,21,43,44,
                                  21,46,47,21,49,50,21,52,53};

// ---------------- prep: betas transposes + rodrigues + pf^T ----------------
__global__ __launch_bounds__(256) void k_prep(
    const float* __restrict__ sp, const float* __restrict__ fe, const float* __restrict__ be,
    const float* __restrict__ eye, const float* __restrict__ jaw,
    const float* __restrict__ lhp, const float* __restrict__ rhp,
    const float* __restrict__ gp, const float* __restrict__ bp,
    float* __restrict__ bTf, float* __restrict__ bTs,
    float* __restrict__ rot, float* __restrict__ pTf, float* __restrict__ pTl,
    float* __restrict__ pTr, float* __restrict__ pTs)
{
  int t = blockIdx.x*256 + threadIdx.x;
  if (t < 2*KSH*NB) {
    int which = t / (KSH*NB);
    int r = t % (KSH*NB);
    int l = r / NB, b = r % NB;
    float v;
    if (which==0) v = (l<300)? sp[b*300+l] : fe[b*50+(l-300)];
    else          v = (l<300)? sp[b*300+l] : be[b*50+(l-300)];
    if (which==0) bTf[l*NB+b] = v; else bTs[l*NB+b] = v;
    return;
  }
  t -= 2*KSH*NB;
  if (t >= 92*NB) return;
  int b = t / 92, jj = t % 92;
  int model, j;
  if (jj < 5)       { model=0; j=jj; }
  else if (jj < 21) { model=1; j=jj-5; }
  else if (jj < 37) { model=2; j=jj-21; }
  else              { model=3; j=jj-37; }
  float ax=0.f, ay=0.f, az=0.f;
  if (model==0) {
    if (j==2){ ax=jaw[b*3]; ay=jaw[b*3+1]; az=jaw[b*3+2]; }
    else if (j==3){ ax=eye[b*6]; ay=eye[b*6+1]; az=eye[b*6+2]; }
    else if (j==4){ ax=eye[b*6+3]; ay=eye[b*6+4]; az=eye[b*6+5]; }
  } else if (model==1) {
    if (j>0){ int o=(b*15+(j-1))*3; ax=lhp[o]; ay=lhp[o+1]; az=lhp[o+2]; }
  } else if (model==2) {
    if (j>0){ int o=(b*15+(j-1))*3; ax=rhp[o]; ay=rhp[o+1]; az=rhp[o+2]; }
  } else {
    if (j==0){ ax=gp[b*3]; ay=gp[b*3+1]; az=gp[b*3+2]; }
    else if (j<=21){ int o=(b*21+(j-1))*3; ax=bp[o]; ay=bp[o+1]; az=bp[o+2]; }
  }
  float a2 = ax*ax+ay*ay+az*az + 1e-8f;
  float ang = sqrtf(a2);
  float inv = 1.f/ang;
  float nx=ax*inv, ny=ay*inv, nz=az*inv;
  float s = sinf(ang), c = cosf(ang);
  float n2 = nx*nx+ny*ny+nz*nz;
  float oc = 1.f - c;
  float R[9];
  R[0] = 1.f + oc*(nx*nx - n2);
  R[1] = -s*nz + oc*(nx*ny);
  R[2] =  s*ny + oc*(nx*nz);
  R[3] =  s*nz + oc*(ny*nx);
  R[4] = 1.f + oc*(ny*ny - n2);
  R[5] = -s*nx + oc*(ny*nz);
  R[6] = -s*ny + oc*(nz*nx);
  R[7] =  s*nx + oc*(nz*ny);
  R[8] = 1.f + oc*(nz*nz - n2);
  float* rr = rot + ((size_t)(b*92+jj))*9;
  #pragma unroll
  for (int e=0;e<9;e++) rr[e]=R[e];
  if (j>0) {
    float* pT = (model==0)?pTf:(model==1)?pTl:(model==2)?pTr:pTs;
    int kbase = (j-1)*9;
    #pragma unroll
    for (int e=0;e<9;e++) {
      float v = R[e] - ((e==0||e==4||e==8)?1.f:0.f);
      pT[(kbase+e)*NB + b] = v;
    }
  }
}

// ---------------- GEMM: out[b][n] = tmpl[n] + sum_k S[n][k]*bT[k][b] -------
__global__ __launch_bounds__(256) void k_gemm_shaped(
    const float* __restrict__ S, const float* __restrict__ bT,
    const float* __restrict__ tmpl, float* __restrict__ out, int N, int K)
{
  __shared__ __align__(16) float sT[64*36];
  __shared__ __align__(16) float pfc[32*NB];
  int tid = threadIdx.x;
  int n0 = blockIdx.x*64;
  float acc[4][8];
  #pragma unroll
  for (int i=0;i<4;i++)
    #pragma unroll
    for (int jn=0;jn<8;jn++) acc[i][jn]=0.f;
  int bg = tid & 31, ng = tid >> 5;
  int b0 = bg*4, nl0 = ng*8;
  int nch = (K+31)>>5;
  for (int ch=0; ch<nch; ch++) {
    int k0 = ch*32;
    __syncthreads();
    { // stage S tile [64 rows][32 k], row-major in LDS (stride 36)
      int r = tid>>2, kq = (tid&3)*8;
      int n = n0 + r;
      #pragma unroll
      for (int i=0;i<8;i++) {
        int k = k0 + kq + i;
        float v = 0.f;
        if (n < N && k < K) v = S[(size_t)n*K + k];
        sT[r*36 + kq + i] = v;
      }
    }
    { // stage pf tile [32][128] — contiguous copy from (K,128) layout
      #pragma unroll
      for (int i=0;i<4;i++) {
        int f = tid + i*256;          // float4 index 0..1023
        int k = k0 + (f>>5);
        float4 v = make_float4(0.f,0.f,0.f,0.f);
        if (k < K) v = *(const float4*)(bT + (size_t)k0*NB + (size_t)f*4);
        *(float4*)(pfc + f*4) = v;
      }
    }
    __syncthreads();
    #pragma unroll
    for (int kq=0; kq<8; kq++) {
      float4 p0 = *(const float4*)&pfc[(kq*4+0)*NB + b0];
      float4 p1 = *(const float4*)&pfc[(kq*4+1)*NB + b0];
      float4 p2 = *(const float4*)&pfc[(kq*4+2)*NB + b0];
      float4 p3 = *(const float4*)&pfc[(kq*4+3)*NB + b0];
      #pragma unroll
      for (int nn=0;nn<8;nn++) {
        float4 s4 = *(const float4*)&sT[(nl0+nn)*36 + kq*4];
        acc[0][nn] += p0.x*s4.x + p1.x*s4.y + p2.x*s4.z + p3.x*s4.w;
        acc[1][nn] += p0.y*s4.x + p1.y*s4.y + p2.y*s4.z + p3.y*s4.w;
        acc[2][nn] += p0.z*s4.x + p1.z*s4.y + p2.z*s4.z + p3.z*s4.w;
        acc[3][nn] += p0.w*s4.x + p1.w*s4.y + p2.w*s4.z + p3.w*s4.w;
      }
    }
  }
  #pragma unroll
  for (int bi=0; bi<4; bi++) {
    int b = b0 + bi;
    #pragma unroll
    for (int nn=0; nn<8; nn++) {
      int n = n0 + nl0 + nn;
      if (n < N) out[(size_t)b*N + n] = tmpl[n] + acc[bi][nn];
    }
  }
}

// ------- GEMM (k-major S): out[b][n] += sum_k S[k][n]*pT[k][b] (in-place) --
__global__ __launch_bounds__(256) void k_gemm_pose(
    const float* __restrict__ S, const float* __restrict__ pT,
    float* __restrict__ out, int N, int K)
{
  __shared__ __align__(16) float sK[32*68];
  __shared__ __align__(16) float pfc[32*NB];
  int tid = threadIdx.x;
  int n0 = blockIdx.x*64;
  float acc[4][8];
  #pragma unroll
  for (int i=0;i<4;i++)
    #pragma unroll
    for (int jn=0;jn<8;jn++) acc[i][jn]=0.f;
  int bg = tid & 31, ng = tid >> 5;
  int b0 = bg*4, nl0 = ng*8;
  int nch = (K+31)>>5;
  for (int ch=0; ch<nch; ch++) {
    int k0 = ch*32;
    __syncthreads();
    { // stage S tile [32 k][64 n] (stride 68)
      int kl = tid>>3;
      int k = k0 + kl;
      int cc = (tid&7)*8;
      #pragma unroll
      for (int i=0;i<8;i++) {
        int n = n0 + cc + i;
        float v = 0.f;
        if (k < K && n < N) v = S[(size_t)k*N + n];
        sK[kl*68 + cc + i] = v;
      }
    }
    {
      #pragma unroll
      for (int i=0;i<4;i++) {
        int f = tid + i*256;
        int k = k0 + (f>>5);
        float4 v = make_float4(0.f,0.f,0.f,0.f);
        if (k < K) v = *(const float4*)(pT + (size_t)k0*NB + (size_t)f*4);
        *(float4*)(pfc + f*4) = v;
      }
    }
    __syncthreads();
    #pragma unroll
    for (int kq=0; kq<8; kq++) {
      float4 pv[4];
      #pragma unroll
      for (int kk=0;kk<4;kk++) pv[kk] = *(const float4*)&pfc[(kq*4+kk)*NB + b0];
      #pragma unroll
      for (int kk=0;kk<4;kk++) {
        float4 A4 = *(const float4*)&sK[(kq*4+kk)*68 + nl0];
        float4 B4 = *(const float4*)&sK[(kq*4+kk)*68 + nl0 + 4];
        float sv[8] = {A4.x,A4.y,A4.z,A4.w,B4.x,B4.y,B4.z,B4.w};
        float4 p = pv[kk];
        #pragma unroll
        for (int nn=0;nn<8;nn++) {
          acc[0][nn] += p.x*sv[nn];
          acc[1][nn] += p.y*sv[nn];
          acc[2][nn] += p.z*sv[nn];
          acc[3][nn] += p.w*sv[nn];
        }
      }
    }
  }
  #pragma unroll
  for (int bi=0; bi<4; bi++) {
    int b = b0 + bi;
    #pragma unroll
    for (int nn=0; nn<8; nn++) {
      int n = n0 + nl0 + nn;
      if (n < N) out[(size_t)b*N + n] += acc[bi][nn];
    }
  }
}

// ---------------- joint regression: out[b,j,c] = sum_v Jreg[j,v]*vsh[b,3v+c]
__global__ __launch_bounds__(256) void k_jreg(
    const float* __restrict__ Jreg, const float* __restrict__ vsh,
    const float* __restrict__ joff, float* __restrict__ out,
    int NJ, int V, int JG)
{
  int b = blockIdx.x;
  int jg0 = blockIdx.y * JG;
  int tid = threadIdx.x;
  float acc[11][3];
  #pragma unroll
  for (int jl=0;jl<11;jl++){ acc[jl][0]=0.f; acc[jl][1]=0.f; acc[jl][2]=0.f; }
  const float* vb = vsh + (size_t)b*V*3;
  for (int v=tid; v<V; v+=256) {
    float x0 = vb[3*v], x1 = vb[3*v+1], x2 = vb[3*v+2];
    #pragma unroll
    for (int jl=0;jl<11;jl++) {
      if (jl < JG && jg0+jl < NJ) {
        float w = Jreg[(size_t)(jg0+jl)*V + v];
        acc[jl][0] += w*x0; acc[jl][1] += w*x1; acc[jl][2] += w*x2;
      }
    }
  }
  #pragma unroll
  for (int jl=0;jl<11;jl++)
    #pragma unroll
    for (int c=0;c<3;c++)
      #pragma unroll
      for (int off=32; off; off>>=1)
        acc[jl][c] += __shfl_down(acc[jl][c], off, 64);
  __shared__ float red[4][33];
  int wave = tid>>6, lane = tid&63;
  if (lane==0) {
    #pragma unroll
    for (int jl=0;jl<11;jl++)
      #pragma unroll
      for (int c=0;c<3;c++) red[wave][jl*3+c] = acc[jl][c];
  }
  __syncthreads();
  if (tid < 33) {
    int jl = tid/3, c = tid%3;
    if (jl < JG && jg0+jl < NJ) {
      float sum = red[0][tid]+red[1][tid]+red[2][tid]+red[3][tid];
      size_t oi = ((size_t)b*NJ + jg0+jl)*3 + c;
      if (joff) sum += joff[oi];
      out[oi] = sum;
    }
  }
}

// ---------------- mano shape (batch-independent) ---------------------------
__global__ __launch_bounds__(256) void k_mano_shaped(
    const float* __restrict__ tmpl, const float* __restrict__ sdirs,
    const float* __restrict__ mb_, const float* __restrict__ Jreg,
    float* __restrict__ vsh, float* __restrict__ Jm)
{
  __shared__ float vs[NM3v];
  __shared__ float mb[10];
  int tid = threadIdx.x;
  if (tid<10) mb[tid]=mb_[tid];
  __syncthreads();
  for (int n=tid; n<NM3v; n+=256) {
    float a = tmpl[n];
    #pragma unroll
    for (int l=0;l<10;l++) a += sdirs[n*10+l]*mb[l];
    vs[n]=a; vsh[n]=a;
  }
  __syncthreads();
  if (tid<48) {
    int j=tid/3, c=tid%3;
    float s=0.f;
    for (int v=0;v<VM;v++) s += Jreg[j*VM+v]*vs[v*3+c];
    Jm[tid]=s;
  }
}

// ---------------- forward kinematics (all 4 models) ------------------------
__global__ __launch_bounds__(64) void k_fk(
    const float* __restrict__ rot_all, const float* __restrict__ Jf,
    const float* __restrict__ Jm, const float* __restrict__ tbj,
    float* __restrict__ Af, float* __restrict__ Al, float* __restrict__ Ar,
    float* __restrict__ As, float* __restrict__ pJf)
{
  int b = blockIdx.x;
  int model = blockIdx.y;
  int NJ, roff; const int* par; const float* J; float* A;
  if (model==0){ NJ=5;  roff=0;  par=PAR_F; J=Jf + (size_t)b*15;  A=Af + (size_t)b*60;  }
  else if (model==1){ NJ=16; roff=5;  par=PAR_M; J=Jm;            A=Al + (size_t)b*192; }
  else if (model==2){ NJ=16; roff=21; par=PAR_M; J=Jm;            A=Ar + (size_t)b*192; }
  else { NJ=55; roff=37; par=PAR_S; J=tbj + (size_t)b*165; A=As + (size_t)b*660; }
  const float* rb = rot_all + ((size_t)(b*92 + roff))*9;
  __shared__ float ch[55*12];
  __shared__ float JL[55*3];
  int tid = threadIdx.x;
  for (int i=tid;i<NJ*3;i+=64) JL[i]=J[i];
  __syncthreads();
  for (int j=0;j<NJ;j++) {
    if (tid<12) {
      int m=tid>>2, nn=tid&3;
      float v;
      if (j==0) v = (nn<3)? rb[m*3+nn] : JL[m];
      else {
        int p = par[j];
        const float* Rj = rb + j*9;
        float t0,t1,t2;
        if (nn<3){ t0=Rj[nn]; t1=Rj[3+nn]; t2=Rj[6+nn]; }
        else { t0=JL[j*3]-JL[p*3]; t1=JL[j*3+1]-JL[p*3+1]; t2=JL[j*3+2]-JL[p*3+2]; }
        const float* cp = ch + p*12 + m*4;
        v = cp[0]*t0 + cp[1]*t1 + cp[2]*t2;
        if (nn==3) v += cp[3];
      }
      ch[j*12+tid] = v;
    }
    __syncthreads();
  }
  if (model==0 && tid < 15) {
    int j=tid/3, c=tid%3;
    pJf[(size_t)b*15 + tid] = ch[j*12 + c*4 + 3];
  }
  for (int i=tid; i<NJ*12; i+=64) {
    int j=i/12, e=i%12, m=e>>2, nn=e&3;
    float v = ch[i];
    if (nn==3) {
      const float* cj = ch + j*12 + m*4;
      v -= cj[0]*JL[j*3] + cj[1]*JL[j*3+1] + cj[2]*JL[j*3+2];
    }
    A[i] = v;
  }
}

// ---------------- flame skin at head_index + scatter into new_t ------------
__global__ __launch_bounds__(256) void k_head(
    const float* __restrict__ vpf, const float* __restrict__ Af,
    const float* __restrict__ Wf, const float* __restrict__ rey,
    const float* __restrict__ ley, const float* __restrict__ eyep,
    const float* __restrict__ hscale, const float* __restrict__ hoff,
    const float* __restrict__ pJf, const float* __restrict__ tbj,
    const int* __restrict__ hidx, const int* __restrict__ s2f,
    float* __restrict__ new_t)
{
  int b = blockIdx.y;
  int i = blockIdx.x*256 + threadIdx.x;
  __shared__ float AL[60];
  __shared__ float mm[3];
  if (threadIdx.x < 60) AL[threadIdx.x] = Af[(size_t)b*60 + threadIdx.x];
  if (threadIdx.x < 3) {
    int c = threadIdx.x;
    float hm = 0.5f*(pJf[(size_t)b*15+9+c] + pJf[(size_t)b*15+12+c]);
    float tm = 0.5f*(tbj[(size_t)b*165 + 69 + c] + tbj[(size_t)b*165 + 72 + c]);
    mm[c] = tm - hm;
  }
  __syncthreads();
  if (i >= NHD) return;
  int v = hidx[i];
  float w[5];
  #pragma unroll
  for (int j=0;j<5;j++) w[j] = Wf[v*5+j];
  float T[12];
  #pragma unroll
  for (int e=0;e<12;e++){
    float s=0.f;
    #pragma unroll
    for (int j=0;j<5;j++) s += w[j]*AL[j*12+e];
    T[e]=s;
  }
  const float* vp = vpf + (size_t)b*NF3v + 3*v;
  float x0=vp[0], x1=vp[1], x2=vp[2];
  float el0 = eyep[b*2], el1 = eyep[b*2+1];
  float hs = hscale[b];
  int col = s2f[v];
  float* dst = new_t + (size_t)b*NS3v + 3*col;
  #pragma unroll
  for (int c=0;c<3;c++){
    float r = T[c*4]*x0 + T[c*4+1]*x1 + T[c*4+2]*x2 + T[c*4+3];
    r += rey[3*v+c]*el1 + ley[3*v+c]*el0;
    r = r*hs + hoff[b*3+c];
    dst[c] = r + mm[c];
  }
}

// ---------------- mano pose+skin + scatter into new_t ----------------------
__global__ __launch_bounds__(256) void k_mano_skin(
    const float* __restrict__ vshm, const float* __restrict__ pdirs,
    const float* __restrict__ pTl, const float* __restrict__ pTr,
    const float* __restrict__ Al, const float* __restrict__ Ar,
    const float* __restrict__ Wm, const float* __restrict__ Jm,
    const float* __restrict__ lsc, const float* __restrict__ loffp,
    const float* __restrict__ rsc, const float* __restrict__ roffp,
    const float* __restrict__ tbj,
    const int* __restrict__ s2ml, const int* __restrict__ s2mr,
    float* __restrict__ new_t)
{
  int hand = blockIdx.z;
  int b = blockIdx.y;
  int v = blockIdx.x*256 + threadIdx.x;
  const float* pT = hand? pTr : pTl;
  const float* A  = (hand? Ar : Al) + (size_t)b*192;
  __shared__ float AL[192];
  __shared__ float PF[KPM];
  if (threadIdx.x < 192) AL[threadIdx.x] = A[threadIdx.x];
  if (threadIdx.x >= 192 && threadIdx.x < 192+64) {
    for (int k = threadIdx.x - 192; k < KPM; k += 64) PF[k] = pT[k*NB + b];
  }
  __syncthreads();
  if (v >= VM) return;
  float vp0=vshm[3*v], vp1=vshm[3*v+1], vp2=vshm[3*v+2];
  for (int k=0;k<KPM;k++) {
    float p = PF[k];
    vp0 += p * pdirs[(size_t)k*NM3v + 3*v];
    vp1 += p * pdirs[(size_t)k*NM3v + 3*v+1];
    vp2 += p * pdirs[(size_t)k*NM3v + 3*v+2];
  }
  float T[12];
  #pragma unroll
  for (int e=0;e<12;e++) T[e]=0.f;
  for (int j=0;j<16;j++){
    float w = Wm[v*16+j];
    #pragma unroll
    for (int e=0;e<12;e++) T[e] += w*AL[j*12+e];
  }
  float sc = hand? rsc[b] : lsc[b];
  const float* of = hand? (roffp+b*3) : (loffp+b*3);
  const float* tb = tbj + (size_t)b*165 + (hand?21:20)*3;
  int col = (hand? s2mr : s2ml)[v];
  float* dst = new_t + (size_t)b*NS3v + 3*col;
  #pragma unroll
  for (int c=0;c<3;c++){
    float r = T[c*4]*vp0 + T[c*4+1]*vp1 + T[c*4+2]*vp2 + T[c*4+3];
    r = r*sc + of[c];
    r = r - Jm[c];
    if (hand==0 && c==0) r = -r;
    dst[c] = r + tb[c];
  }
}

// ---------------- final 55-joint skin --------------------------------------
#define SKV 192
__global__ __launch_bounds__(256) void k_skin(
    const float* __restrict__ W, const float* __restrict__ As,
    const float* __restrict__ vposed, float* __restrict__ outp)
{
  __shared__ __align__(16) float WL[SKV*60];
  __shared__ __align__(16) float AL[4*672];
  int tid = threadIdx.x;
  int v0 = blockIdx.x*SKV;
  int b0 = blockIdx.y*4;
  for (int i=tid; i<SKV*55; i+=256) {
    int vl = i/55, j = i%55;
    int v = v0+vl;
    WL[vl*60+j] = (v<VS)? W[(size_t)v*55+j] : 0.f;
  }
  for (int i=tid;i<SKV;i+=256) WL[i*60+55]=0.f;
  for (int i=tid; i<4*660; i+=256) {
    int bl = i/660, r = i%660;
    AL[bl*672 + r] = As[((size_t)(b0+bl))*660 + r];
  }
  if (tid < 48) {
    int bl=tid/12, e=tid%12;
    AL[bl*672 + 660 + e] = 0.f;
  }
  __syncthreads();
  int bl = tid>>6, lane = tid&63;
  int b = b0 + bl;
  const float* ALb = AL + bl*672;
  float T[3][12];
  #pragma unroll
  for (int q=0;q<3;q++)
    #pragma unroll
    for (int e=0;e<12;e++) T[q][e]=0.f;
  #pragma unroll
  for (int jq=0; jq<14; jq++) {
    float4 w4[3];
    #pragma unroll
    for (int q=0;q<3;q++) w4[q] = *(const float4*)&WL[(lane + 64*q)*60 + jq*4];
    #pragma unroll
    for (int jj=0;jj<4;jj++) {
      int j = jq*4+jj;
      float4 a0 = *(const float4*)&ALb[j*12];
      float4 a1 = *(const float4*)&ALb[j*12+4];
      float4 a2 = *(const float4*)&ALb[j*12+8];
      #pragma unroll
      for (int q=0;q<3;q++) {
        float wa[4] = {w4[q].x, w4[q].y, w4[q].z, w4[q].w};
        float w = wa[jj];
        T[q][0]+=w*a0.x; T[q][1]+=w*a0.y; T[q][2]+=w*a0.z;  T[q][3]+=w*a0.w;
        T[q][4]+=w*a1.x; T[q][5]+=w*a1.y; T[q][6]+=w*a1.z;  T[q][7]+=w*a1.w;
        T[q][8]+=w*a2.x; T[q][9]+=w*a2.y; T[q][10]+=w*a2.z; T[q][11]+=w*a2.w;
      }
    }
  }
  #pragma unroll
  for (int q=0;q<3;q++) {
    int v = v0 + lane + 64*q;
    if (v < VS) {
      const float* vp = vposed + (size_t)b*NS3v + 3*v;
      float x0=vp[0], x1=vp[1], x2=vp[2];
      float* dst = outp + (size_t)b*NS3v + 3*v;
      #pragma unroll
      for (int c=0;c<3;c++)
        dst[c] = T[q][c*4]*x0 + T[q][c*4+1]*x1 + T[q][c*4+2]*x2 + T[q][c*4+3];
    }
  }
}

extern "C" void kernel_launch(void* const* d_in, const int* in_sizes, int n_in,
                              void* d_out, int out_size, void* d_ws, size_t ws_size,
                              hipStream_t stream) {
  const float* sp   = (const float*)d_in[0];
  const float* fe   = (const float*)d_in[1];
  const float* eye  = (const float*)d_in[2];
  const float* jaw  = (const float*)d_in[3];
  const float* eyep = (const float*)d_in[4];
  const float* hsc  = (const float*)d_in[5];
  const float* hoff = (const float*)d_in[6];
  const float* lhp  = (const float*)d_in[7];
  const float* rhp  = (const float*)d_in[8];
  const float* lsc  = (const float*)d_in[9];
  const float* loff = (const float*)d_in[10];
  const float* rsc  = (const float*)d_in[11];
  const float* roff = (const float*)d_in[12];
  const float* be   = (const float*)d_in[13];
  const float* gp   = (const float*)d_in[14];
  const float* bp   = (const float*)d_in[15];
  const float* joff = (const float*)d_in[16];
  const float* mb   = (const float*)d_in[17];
  const float* f_tmpl = (const float*)d_in[18];
  const float* f_sd   = (const float*)d_in[19];
  const float* f_pd   = (const float*)d_in[20];
  const float* f_jr   = (const float*)d_in[21];
  const float* f_W    = (const float*)d_in[22];
  const float* rey    = (const float*)d_in[23];
  const float* ley    = (const float*)d_in[24];
  const float* m_tmpl = (const float*)d_in[25];
  const float* m_sd   = (const float*)d_in[26];
  const float* m_pd   = (const float*)d_in[27];
  const float* m_jr   = (const float*)d_in[28];
  const float* m_W    = (const float*)d_in[29];
  const float* s_tmpl = (const float*)d_in[30];
  const float* s_sd   = (const float*)d_in[31];
  const float* s_pd   = (const float*)d_in[32];
  const float* s_jr   = (const float*)d_in[33];
  const float* s_W    = (const float*)d_in[34];
  // setup_inputs() dict order (NOT reference-signature order!):
  //   35: smplx2flame_ind (VF), 36: smplx2mano_left (VM),
  //   37: smplx2mano_right (VM), 38: head_index (3000)
  const int* s2f  = (const int*)d_in[35];
  const int* s2ml = (const int*)d_in[36];
  const int* s2mr = (const int*)d_in[37];
  const int* hidx = (const int*)d_in[38];
  float* outp = (float*)d_out;

  // newt (v_template/v_posed, NB*NS3v floats) lives in d_out — exactly
  // out_size elements; final k_skin reads/writes it in-place (same-thread
  // read-before-write, no cross-thread aliasing). Keeps ws usage ~9.6 MB.
  float* newt = outp;

  float* w = (float*)d_ws;
  size_t o = 0;
  auto A_ = [&](size_t n){ size_t r = o; o += (n + 3) & ~(size_t)3; return r; };
  float* bTf  = w + A_((size_t)KSH*NB);
  float* bTs  = w + A_((size_t)KSH*NB);
  float* pTf  = w + A_((size_t)KPF*NB);
  float* pTl  = w + A_((size_t)KPM*NB);
  float* pTr  = w + A_((size_t)KPM*NB);
  float* pTs  = w + A_((size_t)KPS*NB);
  float* rot  = w + A_((size_t)NB*92*9);
  float* vshf = w + A_((size_t)NB*NF3v);
  float* Jf   = w + A_((size_t)NB*15);
  float* pJf  = w + A_((size_t)NB*15);
  float* Af   = w + A_((size_t)NB*60);
  float* vshm = w + A_((size_t)NM3v);
  float* Jm   = w + A_((size_t)48);
  float* Al   = w + A_((size_t)NB*192);
  float* Ar   = w + A_((size_t)NB*192);
  float* tbj  = w + A_((size_t)NB*165);
  float* As   = w + A_((size_t)NB*660);
  (void)ws_size; (void)n_in; (void)in_sizes; (void)out_size;

  // 1. prep: transposes + rodrigues
  {
    int total = 2*KSH*NB + 92*NB;
    k_prep<<<(total+255)/256, 256, 0, stream>>>(sp, fe, be, eye, jaw, lhp, rhp, gp, bp,
                                                bTf, bTs, rot, pTf, pTl, pTr, pTs);
  }
  // 2. smplx shape GEMM -> new_t (in d_out)
  k_gemm_shaped<<<(NS3v+63)/64, 256, 0, stream>>>(s_sd, bTs, s_tmpl, newt, NS3v, KSH);
  // 3. smplx joint regression (+joints_offset) -> tbj
  k_jreg<<<dim3(NB,5), 256, 0, stream>>>(s_jr, newt, joff, tbj, 55, VS, 11);
  // 4. flame shape GEMM -> vshf
  k_gemm_shaped<<<(NF3v+63)/64, 256, 0, stream>>>(f_sd, bTf, f_tmpl, vshf, NF3v, KSH);
  // 5. flame joint regression -> Jf
  k_jreg<<<dim3(NB,1), 256, 0, stream>>>(f_jr, vshf, nullptr, Jf, 5, VF, 5);
  // 6. mano shape (batch independent) -> vshm, Jm
  k_mano_shaped<<<1, 256, 0, stream>>>(m_tmpl, m_sd, mb, m_jr, vshm, Jm);
  // 7. FK all models -> Af, Al, Ar, As, pJf
  k_fk<<<dim3(NB,4), 64, 0, stream>>>(rot, Jf, Jm, tbj, Af, Al, Ar, As, pJf);
  // 8. flame pose GEMM in-place -> vshf becomes v_posed_f
  k_gemm_pose<<<(NF3v+63)/64, 256, 0, stream>>>(f_pd, pTf, vshf, NF3v, KPF);
  // 9. flame skin at head_index -> scatter into new_t
  k_head<<<dim3((NHD+255)/256, NB), 256, 0, stream>>>(vshf, Af, f_W, rey, ley, eyep,
                                                      hsc, hoff, pJf, tbj, hidx, s2f, newt);
  // 10. mano pose+skin both hands -> scatter into new_t
  k_mano_skin<<<dim3((VM+255)/256, NB, 2), 256, 0, stream>>>(vshm, m_pd, pTl, pTr, Al, Ar,
                                                             m_W, Jm, lsc, loff, rsc, roff,
                                                             tbj, s2ml, s2mr, newt);
  // 11. smplx pose GEMM in-place -> new_t becomes v_posed
  k_gemm_pose<<<(NS3v+63)/64, 256, 0, stream>>>(s_pd, pTs, newt, NS3v, KPS);
  // 12. final skin -> d_out (in-place over newt)
  k_skin<<<dim3((VS+SKV-1)/SKV, NB/4), 256, 0, stream>>>(s_W, As, newt, outp);
}

// Round 8
// 994.341 us; speedup vs baseline: 1.8043x; 1.8043x over previous
//
#include <hip/hip_runtime.h>
#include <math.h>

#define NB 128
#define VS 10475
#define VF 5023
#define VM 778
#define NS3v (VS*3)   // 31425
#define NF3v (VF*3)   // 15069
#define NM3v (VM*3)   // 2334
#define KSH 350
#define KPF 36
#define KPM 135
#define KPS 486
#define NHD 3000

__device__ const int PAR_F[5]  = {-1,0,1,1,1};
__device__ const int PAR_M[16] = {-1,0,1,2,0,4,5,0,7,8,0,10,11,0,13,14};
__device__ const int PAR_S[55] = {-1,0,0,0,1,2,3,4,5,6,7,8,9,9,9,12,13,14,16,17,18,19,15,15,15,
                                  20,25,26,20,28,29,20,31,32,20,34,35,20,37,38,21,40,41,21,43,44,
                                  21,46,47,21,49,50,21,52,53};

// ---------------- prep: betas transposes + rodrigues + pf^T ----------------
__global__ __launch_bounds__(256) void k_prep(
    const float* __restrict__ sp, const float* __restrict__ fe, const float* __restrict__ be,
    const float* __restrict__ eye, const float* __restrict__ jaw,
    const float* __restrict__ lhp, const float* __restrict__ rhp,
    const float* __restrict__ gp, const float* __restrict__ bp,
    float* __restrict__ bTf, float* __restrict__ bTs,
    float* __restrict__ rot, float* __restrict__ pTf, float* __restrict__ pTl,
    float* __restrict__ pTr, float* __restrict__ pTs)
{
  int t = blockIdx.x*256 + threadIdx.x;
  if (t < 2*KSH*NB) {
    int which = t / (KSH*NB);
    int r = t % (KSH*NB);
    int l = r / NB, b = r % NB;
    float v;
    if (which==0) v = (l<300)? sp[b*300+l] : fe[b*50+(l-300)];
    else          v = (l<300)? sp[b*300+l] : be[b*50+(l-300)];
    if (which==0) bTf[l*NB+b] = v; else bTs[l*NB+b] = v;
    return;
  }
  t -= 2*KSH*NB;
  if (t >= 92*NB) return;
  int b = t / 92, jj = t % 92;
  int model, j;
  if (jj < 5)       { model=0; j=jj; }
  else if (jj < 21) { model=1; j=jj-5; }
  else if (jj < 37) { model=2; j=jj-21; }
  else              { model=3; j=jj-37; }
  float ax=0.f, ay=0.f, az=0.f;
  if (model==0) {
    if (j==2){ ax=jaw[b*3]; ay=jaw[b*3+1]; az=jaw[b*3+2]; }
    else if (j==3){ ax=eye[b*6]; ay=eye[b*6+1]; az=eye[b*6+2]; }
    else if (j==4){ ax=eye[b*6+3]; ay=eye[b*6+4]; az=eye[b*6+5]; }
  } else if (model==1) {
    if (j>0){ int o=(b*15+(j-1))*3; ax=lhp[o]; ay=lhp[o+1]; az=lhp[o+2]; }
  } else if (model==2) {
    if (j>0){ int o=(b*15+(j-1))*3; ax=rhp[o]; ay=rhp[o+1]; az=rhp[o+2]; }
  } else {
    if (j==0){ ax=gp[b*3]; ay=gp[b*3+1]; az=gp[b*3+2]; }
    else if (j<=21){ int o=(b*21+(j-1))*3; ax=bp[o]; ay=bp[o+1]; az=bp[o+2]; }
  }
  float a2 = ax*ax+ay*ay+az*az + 1e-8f;
  float ang = sqrtf(a2);
  float inv = 1.f/ang;
  float nx=ax*inv, ny=ay*inv, nz=az*inv;
  float s = sinf(ang), c = cosf(ang);
  float n2 = nx*nx+ny*ny+nz*nz;
  float oc = 1.f - c;
  float R[9];
  R[0] = 1.f + oc*(nx*nx - n2);
  R[1] = -s*nz + oc*(nx*ny);
  R[2] =  s*ny + oc*(nx*nz);
  R[3] =  s*nz + oc*(ny*nx);
  R[4] = 1.f + oc*(ny*ny - n2);
  R[5] = -s*nx + oc*(ny*nz);
  R[6] = -s*ny + oc*(nz*nx);
  R[7] =  s*nx + oc*(nz*ny);
  R[8] = 1.f + oc*(nz*nz - n2);
  float* rr = rot + ((size_t)(b*92+jj))*9;
  #pragma unroll
  for (int e=0;e<9;e++) rr[e]=R[e];
  if (j>0) {
    float* pT = (model==0)?pTf:(model==1)?pTl:(model==2)?pTr:pTs;
    int kbase = (j-1)*9;
    #pragma unroll
    for (int e=0;e<9;e++) {
      float v = R[e] - ((e==0||e==4||e==8)?1.f:0.f);
      pT[(kbase+e)*NB + b] = v;
    }
  }
}

// ---------------- GEMM: out[b][n] = tmpl[n] + sum_k S[n][k]*bT[k][b] -------
__global__ __launch_bounds__(256) void k_gemm_shaped(
    const float* __restrict__ S, const float* __restrict__ bT,
    const float* __restrict__ tmpl, float* __restrict__ out, int N, int K)
{
  __shared__ __align__(16) float sT[64*36];
  __shared__ __align__(16) float pfc[32*NB];
  int tid = threadIdx.x;
  int n0 = blockIdx.x*64;
  float acc[4][8];
  #pragma unroll
  for (int i=0;i<4;i++)
    #pragma unroll
    for (int jn=0;jn<8;jn++) acc[i][jn]=0.f;
  int bg = tid & 31, ng = tid >> 5;
  int b0 = bg*4, nl0 = ng*8;
  int nch = (K+31)>>5;
  for (int ch=0; ch<nch; ch++) {
    int k0 = ch*32;
    __syncthreads();
    { // stage S tile [64 rows][32 k], row-major in LDS (stride 36)
      int r = tid>>2, kq = (tid&3)*8;
      int n = n0 + r;
      #pragma unroll
      for (int i=0;i<8;i++) {
        int k = k0 + kq + i;
        float v = 0.f;
        if (n < N && k < K) v = S[(size_t)n*K + k];
        sT[r*36 + kq + i] = v;
      }
    }
    { // stage pf tile [32][128] — contiguous copy from (K,128) layout
      #pragma unroll
      for (int i=0;i<4;i++) {
        int f = tid + i*256;          // float4 index 0..1023
        int k = k0 + (f>>5);
        float4 v = make_float4(0.f,0.f,0.f,0.f);
        if (k < K) v = *(const float4*)(bT + (size_t)k0*NB + (size_t)f*4);
        *(float4*)(pfc + f*4) = v;
      }
    }
    __syncthreads();
    // unroll 2 (not full): full unroll invites hipcc to hoist all LDS
    // float4 loads -> register spill (observed on k_skin: VGPR=256,
    // 0.7 GB scratch writes/dispatch).
    #pragma unroll 2
    for (int kq=0; kq<8; kq++) {
      float4 p0 = *(const float4*)&pfc[(kq*4+0)*NB + b0];
      float4 p1 = *(const float4*)&pfc[(kq*4+1)*NB + b0];
      float4 p2 = *(const float4*)&pfc[(kq*4+2)*NB + b0];
      float4 p3 = *(const float4*)&pfc[(kq*4+3)*NB + b0];
      #pragma unroll
      for (int nn=0;nn<8;nn++) {
        float4 s4 = *(const float4*)&sT[(nl0+nn)*36 + kq*4];
        acc[0][nn] += p0.x*s4.x + p1.x*s4.y + p2.x*s4.z + p3.x*s4.w;
        acc[1][nn] += p0.y*s4.x + p1.y*s4.y + p2.y*s4.z + p3.y*s4.w;
        acc[2][nn] += p0.z*s4.x + p1.z*s4.y + p2.z*s4.z + p3.z*s4.w;
        acc[3][nn] += p0.w*s4.x + p1.w*s4.y + p2.w*s4.z + p3.w*s4.w;
      }
    }
  }
  #pragma unroll
  for (int bi=0; bi<4; bi++) {
    int b = b0 + bi;
    #pragma unroll
    for (int nn=0; nn<8; nn++) {
      int n = n0 + nl0 + nn;
      if (n < N) out[(size_t)b*N + n] = tmpl[n] + acc[bi][nn];
    }
  }
}

// ------- GEMM (k-major S): out[b][n] += sum_k S[k][n]*pT[k][b] (in-place) --
__global__ __launch_bounds__(256) void k_gemm_pose(
    const float* __restrict__ S, const float* __restrict__ pT,
    float* __restrict__ out, int N, int K)
{
  __shared__ __align__(16) float sK[32*68];
  __shared__ __align__(16) float pfc[32*NB];
  int tid = threadIdx.x;
  int n0 = blockIdx.x*64;
  float acc[4][8];
  #pragma unroll
  for (int i=0;i<4;i++)
    #pragma unroll
    for (int jn=0;jn<8;jn++) acc[i][jn]=0.f;
  int bg = tid & 31, ng = tid >> 5;
  int b0 = bg*4, nl0 = ng*8;
  int nch = (K+31)>>5;
  for (int ch=0; ch<nch; ch++) {
    int k0 = ch*32;
    __syncthreads();
    { // stage S tile [32 k][64 n] (stride 68)
      int kl = tid>>3;
      int k = k0 + kl;
      int cc = (tid&7)*8;
      #pragma unroll
      for (int i=0;i<8;i++) {
        int n = n0 + cc + i;
        float v = 0.f;
        if (k < K && n < N) v = S[(size_t)k*N + n];
        sK[kl*68 + cc + i] = v;
      }
    }
    {
      #pragma unroll
      for (int i=0;i<4;i++) {
        int f = tid + i*256;
        int k = k0 + (f>>5);
        float4 v = make_float4(0.f,0.f,0.f,0.f);
        if (k < K) v = *(const float4*)(pT + (size_t)k0*NB + (size_t)f*4);
        *(float4*)(pfc + f*4) = v;
      }
    }
    __syncthreads();
    #pragma unroll 2
    for (int kq=0; kq<8; kq++) {
      float4 pv[4];
      #pragma unroll
      for (int kk=0;kk<4;kk++) pv[kk] = *(const float4*)&pfc[(kq*4+kk)*NB + b0];
      #pragma unroll
      for (int kk=0;kk<4;kk++) {
        float4 A4 = *(const float4*)&sK[(kq*4+kk)*68 + nl0];
        float4 B4 = *(const float4*)&sK[(kq*4+kk)*68 + nl0 + 4];
        float sv[8] = {A4.x,A4.y,A4.z,A4.w,B4.x,B4.y,B4.z,B4.w};
        float4 p = pv[kk];
        #pragma unroll
        for (int nn=0;nn<8;nn++) {
          acc[0][nn] += p.x*sv[nn];
          acc[1][nn] += p.y*sv[nn];
          acc[2][nn] += p.z*sv[nn];
          acc[3][nn] += p.w*sv[nn];
        }
      }
    }
  }
  #pragma unroll
  for (int bi=0; bi<4; bi++) {
    int b = b0 + bi;
    #pragma unroll
    for (int nn=0; nn<8; nn++) {
      int n = n0 + nl0 + nn;
      if (n < N) out[(size_t)b*N + n] += acc[bi][nn];
    }
  }
}

// ---------------- joint regression: out[b,j,c] = sum_v Jreg[j,v]*vsh[b,3v+c]
__global__ __launch_bounds__(256) void k_jreg(
    const float* __restrict__ Jreg, const float* __restrict__ vsh,
    const float* __restrict__ joff, float* __restrict__ out,
    int NJ, int V, int JG)
{
  int b = blockIdx.x;
  int jg0 = blockIdx.y * JG;
  int tid = threadIdx.x;
  float acc[11][3];
  #pragma unroll
  for (int jl=0;jl<11;jl++){ acc[jl][0]=0.f; acc[jl][1]=0.f; acc[jl][2]=0.f; }
  const float* vb = vsh + (size_t)b*V*3;
  for (int v=tid; v<V; v+=256) {
    float x0 = vb[3*v], x1 = vb[3*v+1], x2 = vb[3*v+2];
    #pragma unroll
    for (int jl=0;jl<11;jl++) {
      if (jl < JG && jg0+jl < NJ) {
        float w = Jreg[(size_t)(jg0+jl)*V + v];
        acc[jl][0] += w*x0; acc[jl][1] += w*x1; acc[jl][2] += w*x2;
      }
    }
  }
  #pragma unroll
  for (int jl=0;jl<11;jl++)
    #pragma unroll
    for (int c=0;c<3;c++)
      #pragma unroll
      for (int off=32; off; off>>=1)
        acc[jl][c] += __shfl_down(acc[jl][c], off, 64);
  __shared__ float red[4][33];
  int wave = tid>>6, lane = tid&63;
  if (lane==0) {
    #pragma unroll
    for (int jl=0;jl<11;jl++)
      #pragma unroll
      for (int c=0;c<3;c++) red[wave][jl*3+c] = acc[jl][c];
  }
  __syncthreads();
  if (tid < 33) {
    int jl = tid/3, c = tid%3;
    if (jl < JG && jg0+jl < NJ) {
      float sum = red[0][tid]+red[1][tid]+red[2][tid]+red[3][tid];
      size_t oi = ((size_t)b*NJ + jg0+jl)*3 + c;
      if (joff) sum += joff[oi];
      out[oi] = sum;
    }
  }
}

// ---------------- mano shape (batch-independent) ---------------------------
__global__ __launch_bounds__(256) void k_mano_shaped(
    const float* __restrict__ tmpl, const float* __restrict__ sdirs,
    const float* __restrict__ mb_, const float* __restrict__ Jreg,
    float* __restrict__ vsh, float* __restrict__ Jm)
{
  __shared__ float vs[NM3v];
  __shared__ float mb[10];
  int tid = threadIdx.x;
  if (tid<10) mb[tid]=mb_[tid];
  __syncthreads();
  for (int n=tid; n<NM3v; n+=256) {
    float a = tmpl[n];
    #pragma unroll
    for (int l=0;l<10;l++) a += sdirs[n*10+l]*mb[l];
    vs[n]=a; vsh[n]=a;
  }
  __syncthreads();
  if (tid<48) {
    int j=tid/3, c=tid%3;
    float s=0.f;
    for (int v=0;v<VM;v++) s += Jreg[j*VM+v]*vs[v*3+c];
    Jm[tid]=s;
  }
}

// ---------------- forward kinematics (all 4 models) ------------------------
__global__ __launch_bounds__(64) void k_fk(
    const float* __restrict__ rot_all, const float* __restrict__ Jf,
    const float* __restrict__ Jm, const float* __restrict__ tbj,
    float* __restrict__ Af, float* __restrict__ Al, float* __restrict__ Ar,
    float* __restrict__ As, float* __restrict__ pJf)
{
  int b = blockIdx.x;
  int model = blockIdx.y;
  int NJ, roff; const int* par; const float* J; float* A;
  if (model==0){ NJ=5;  roff=0;  par=PAR_F; J=Jf + (size_t)b*15;  A=Af + (size_t)b*60;  }
  else if (model==1){ NJ=16; roff=5;  par=PAR_M; J=Jm;            A=Al + (size_t)b*192; }
  else if (model==2){ NJ=16; roff=21; par=PAR_M; J=Jm;            A=Ar + (size_t)b*192; }
  else { NJ=55; roff=37; par=PAR_S; J=tbj + (size_t)b*165; A=As + (size_t)b*660; }
  const float* rb = rot_all + ((size_t)(b*92 + roff))*9;
  __shared__ float ch[55*12];
  __shared__ float JL[55*3];
  int tid = threadIdx.x;
  for (int i=tid;i<NJ*3;i+=64) JL[i]=J[i];
  __syncthreads();
  for (int j=0;j<NJ;j++) {
    if (tid<12) {
      int m=tid>>2, nn=tid&3;
      float v;
      if (j==0) v = (nn<3)? rb[m*3+nn] : JL[m];
      else {
        int p = par[j];
        const float* Rj = rb + j*9;
        float t0,t1,t2;
        if (nn<3){ t0=Rj[nn]; t1=Rj[3+nn]; t2=Rj[6+nn]; }
        else { t0=JL[j*3]-JL[p*3]; t1=JL[j*3+1]-JL[p*3+1]; t2=JL[j*3+2]-JL[p*3+2]; }
        const float* cp = ch + p*12 + m*4;
        v = cp[0]*t0 + cp[1]*t1 + cp[2]*t2;
        if (nn==3) v += cp[3];
      }
      ch[j*12+tid] = v;
    }
    __syncthreads();
  }
  if (model==0 && tid < 15) {
    int j=tid/3, c=tid%3;
    pJf[(size_t)b*15 + tid] = ch[j*12 + c*4 + 3];
  }
  for (int i=tid; i<NJ*12; i+=64) {
    int j=i/12, e=i%12, m=e>>2, nn=e&3;
    float v = ch[i];
    if (nn==3) {
      const float* cj = ch + j*12 + m*4;
      v -= cj[0]*JL[j*3] + cj[1]*JL[j*3+1] + cj[2]*JL[j*3+2];
    }
    A[i] = v;
  }
}

// ---------------- flame skin at head_index + scatter into new_t ------------
__global__ __launch_bounds__(256) void k_head(
    const float* __restrict__ vpf, const float* __restrict__ Af,
    const float* __restrict__ Wf, const float* __restrict__ rey,
    const float* __restrict__ ley, const float* __restrict__ eyep,
    const float* __restrict__ hscale, const float* __restrict__ hoff,
    const float* __restrict__ pJf, const float* __restrict__ tbj,
    const int* __restrict__ hidx, const int* __restrict__ s2f,
    float* __restrict__ new_t)
{
  int b = blockIdx.y;
  int i = blockIdx.x*256 + threadIdx.x;
  __shared__ float AL[60];
  __shared__ float mm[3];
  if (threadIdx.x < 60) AL[threadIdx.x] = Af[(size_t)b*60 + threadIdx.x];
  if (threadIdx.x < 3) {
    int c = threadIdx.x;
    float hm = 0.5f*(pJf[(size_t)b*15+9+c] + pJf[(size_t)b*15+12+c]);
    float tm = 0.5f*(tbj[(size_t)b*165 + 69 + c] + tbj[(size_t)b*165 + 72 + c]);
    mm[c] = tm - hm;
  }
  __syncthreads();
  if (i >= NHD) return;
  int v = hidx[i];
  float w[5];
  #pragma unroll
  for (int j=0;j<5;j++) w[j] = Wf[v*5+j];
  float T[12];
  #pragma unroll
  for (int e=0;e<12;e++){
    float s=0.f;
    #pragma unroll
    for (int j=0;j<5;j++) s += w[j]*AL[j*12+e];
    T[e]=s;
  }
  const float* vp = vpf + (size_t)b*NF3v + 3*v;
  float x0=vp[0], x1=vp[1], x2=vp[2];
  float el0 = eyep[b*2], el1 = eyep[b*2+1];
  float hs = hscale[b];
  int col = s2f[v];
  float* dst = new_t + (size_t)b*NS3v + 3*col;
  #pragma unroll
  for (int c=0;c<3;c++){
    float r = T[c*4]*x0 + T[c*4+1]*x1 + T[c*4+2]*x2 + T[c*4+3];
    r += rey[3*v+c]*el1 + ley[3*v+c]*el0;
    r = r*hs + hoff[b*3+c];
    dst[c] = r + mm[c];
  }
}

// ---------------- mano pose+skin + scatter into new_t ----------------------
__global__ __launch_bounds__(256) void k_mano_skin(
    const float* __restrict__ vshm, const float* __restrict__ pdirs,
    const float* __restrict__ pTl, const float* __restrict__ pTr,
    const float* __restrict__ Al, const float* __restrict__ Ar,
    const float* __restrict__ Wm, const float* __restrict__ Jm,
    const float* __restrict__ lsc, const float* __restrict__ loffp,
    const float* __restrict__ rsc, const float* __restrict__ roffp,
    const float* __restrict__ tbj,
    const int* __restrict__ s2ml, const int* __restrict__ s2mr,
    float* __restrict__ new_t)
{
  int hand = blockIdx.z;
  int b = blockIdx.y;
  int v = blockIdx.x*256 + threadIdx.x;
  const float* pT = hand? pTr : pTl;
  const float* A  = (hand? Ar : Al) + (size_t)b*192;
  __shared__ float AL[192];
  __shared__ float PF[KPM];
  if (threadIdx.x < 192) AL[threadIdx.x] = A[threadIdx.x];
  if (threadIdx.x >= 192 && threadIdx.x < 192+64) {
    for (int k = threadIdx.x - 192; k < KPM; k += 64) PF[k] = pT[k*NB + b];
  }
  __syncthreads();
  if (v >= VM) return;
  float vp0=vshm[3*v], vp1=vshm[3*v+1], vp2=vshm[3*v+2];
  for (int k=0;k<KPM;k++) {
    float p = PF[k];
    vp0 += p * pdirs[(size_t)k*NM3v + 3*v];
    vp1 += p * pdirs[(size_t)k*NM3v + 3*v+1];
    vp2 += p * pdirs[(size_t)k*NM3v + 3*v+2];
  }
  float T[12];
  #pragma unroll
  for (int e=0;e<12;e++) T[e]=0.f;
  for (int j=0;j<16;j++){
    float w = Wm[v*16+j];
    #pragma unroll
    for (int e=0;e<12;e++) T[e] += w*AL[j*12+e];
  }
  float sc = hand? rsc[b] : lsc[b];
  const float* of = hand? (roffp+b*3) : (loffp+b*3);
  const float* tb = tbj + (size_t)b*165 + (hand?21:20)*3;
  int col = (hand? s2mr : s2ml)[v];
  float* dst = new_t + (size_t)b*NS3v + 3*col;
  #pragma unroll
  for (int c=0;c<3;c++){
    float r = T[c*4]*vp0 + T[c*4+1]*vp1 + T[c*4+2]*vp2 + T[c*4+3];
    r = r*sc + of[c];
    r = r - Jm[c];
    if (hand==0 && c==0) r = -r;
    dst[c] = r + tb[c];
  }
}

// ---------------- final 55-joint skin --------------------------------------
// Round 7 fix: previous version (SKV=192, 3 v/thread, full jq unroll) hit
// VGPR=256 + ~1.7 GB scratch spill traffic per dispatch (rocprof: WRITE
// 718 MB vs 16 MB output). #pragma unroll 1 on jq kills the LDS-load hoist;
// 2 v/thread + SKV=128 cuts LDS 56.8->41.5 KB (3 blocks/CU).
#define SKV 128
__global__ __launch_bounds__(256) void k_skin(
    const float* __restrict__ W, const float* __restrict__ As,
    const float* __restrict__ vposed, float* __restrict__ outp)
{
  __shared__ __align__(16) float WL[SKV*60];   // 30720 B
  __shared__ __align__(16) float AL[4*672];    // 10752 B
  int tid = threadIdx.x;
  int v0 = blockIdx.x*SKV;
  int b0 = blockIdx.y*4;
  for (int i=tid; i<SKV*55; i+=256) {
    int vl = i/55, j = i%55;
    int v = v0+vl;
    WL[vl*60+j] = (v<VS)? W[(size_t)v*55+j] : 0.f;
  }
  for (int i=tid;i<SKV;i+=256) WL[i*60+55]=0.f;   // zero pad word 55 (j=55)
  for (int i=tid; i<4*660; i+=256) {
    int bl = i/660, r = i%660;
    AL[bl*672 + r] = As[((size_t)(b0+bl))*660 + r];
  }
  if (tid < 48) {
    int bl=tid/12, e=tid%12;
    AL[bl*672 + 660 + e] = 0.f;                   // zero pad joint 55
  }
  __syncthreads();
  int bl = tid>>6, lane = tid&63;
  int b = b0 + bl;
  const float* ALb = AL + bl*672;
  float T[2][12];
  #pragma unroll
  for (int q=0;q<2;q++)
    #pragma unroll
    for (int e=0;e<12;e++) T[q][e]=0.f;
  #pragma unroll 1
  for (int jq=0; jq<14; jq++) {
    float4 w40 = *(const float4*)&WL[lane*60 + jq*4];
    float4 w41 = *(const float4*)&WL[(lane+64)*60 + jq*4];
    #pragma unroll
    for (int jj=0;jj<4;jj++) {
      int j = jq*4+jj;
      float4 a0 = *(const float4*)&ALb[j*12];
      float4 a1 = *(const float4*)&ALb[j*12+4];
      float4 a2 = *(const float4*)&ALb[j*12+8];
      float w0 = (jj==0)?w40.x:(jj==1)?w40.y:(jj==2)?w40.z:w40.w;
      float w1 = (jj==0)?w41.x:(jj==1)?w41.y:(jj==2)?w41.z:w41.w;
      T[0][0]+=w0*a0.x; T[0][1]+=w0*a0.y; T[0][2] +=w0*a1.x; T[0][3] +=w0*a1.y;
      T[0][4]+=w0*a0.z; T[0][5]+=w0*a0.w; T[0][6] +=w0*a1.z; T[0][7] +=w0*a1.w;
      T[0][8]+=w0*a2.x; T[0][9]+=w0*a2.y; T[0][10]+=w0*a2.z; T[0][11]+=w0*a2.w;
      T[1][0]+=w1*a0.x; T[1][1]+=w1*a0.y; T[1][2] +=w1*a1.x; T[1][3] +=w1*a1.y;
      T[1][4]+=w1*a0.z; T[1][5]+=w1*a0.w; T[1][6] +=w1*a1.z; T[1][7] +=w1*a1.w;
      T[1][8]+=w1*a2.x; T[1][9]+=w1*a2.y; T[1][10]+=w1*a2.z; T[1][11]+=w1*a2.w;
    }
  }
  // NOTE: T[q] element e corresponds to A element mapping used above:
  // A row-major 12 elems per joint: a0=(A0,A1,A2,A3), a1=(A4..A7), a2=(A8..A11)
  // T indices were permuted in accumulation; un-permute on apply:
  // T[q][0..3] hold A0,A1,A4,A5? -- keep identical mapping as accumulation:
  // Actually simpler: Ti[e] accumulated as: [0]=A0,[1]=A1,[2]=A4,[3]=A5,
  // [4]=A2,[5]=A3,[6]=A6,[7]=A7,[8]=A8,[9]=A9,[10]=A10,[11]=A11
  #pragma unroll
  for (int q=0;q<2;q++) {
    int v = v0 + lane + 64*q;
    if (v < VS) {
      const float* vp = vposed + (size_t)b*NS3v + 3*v;
      float x0=vp[0], x1=vp[1], x2=vp[2];
      float* dst = outp + (size_t)b*NS3v + 3*v;
      // row0 = A0*x0+A1*x1+A2*x2+A3 = T[q][0]*x0+T[q][1]*x1+T[q][4]*x2+T[q][5]
      dst[0] = T[q][0]*x0 + T[q][1]*x1 + T[q][4]*x2 + T[q][5];
      // row1 = A4*x0+A5*x1+A6*x2+A7 = T[q][2]*x0+T[q][3]*x1+T[q][6]*x2+T[q][7]
      dst[1] = T[q][2]*x0 + T[q][3]*x1 + T[q][6]*x2 + T[q][7];
      // row2 = A8*x0+A9*x1+A10*x2+A11
      dst[2] = T[q][8]*x0 + T[q][9]*x1 + T[q][10]*x2 + T[q][11];
    }
  }
}

extern "C" void kernel_launch(void* const* d_in, const int* in_sizes, int n_in,
                              void* d_out, int out_size, void* d_ws, size_t ws_size,
                              hipStream_t stream) {
  const float* sp   = (const float*)d_in[0];
  const float* fe   = (const float*)d_in[1];
  const float* eye  = (const float*)d_in[2];
  const float* jaw  = (const float*)d_in[3];
  const float* eyep = (const float*)d_in[4];
  const float* hsc  = (const float*)d_in[5];
  const float* hoff = (const float*)d_in[6];
  const float* lhp  = (const float*)d_in[7];
  const float* rhp  = (const float*)d_in[8];
  const float* lsc  = (const float*)d_in[9];
  const float* loff = (const float*)d_in[10];
  const float* rsc  = (const float*)d_in[11];
  const float* roff = (const float*)d_in[12];
  const float* be   = (const float*)d_in[13];
  const float* gp   = (const float*)d_in[14];
  const float* bp   = (const float*)d_in[15];
  const float* joff = (const float*)d_in[16];
  const float* mb   = (const float*)d_in[17];
  const float* f_tmpl = (const float*)d_in[18];
  const float* f_sd   = (const float*)d_in[19];
  const float* f_pd   = (const float*)d_in[20];
  const float* f_jr   = (const float*)d_in[21];
  const float* f_W    = (const float*)d_in[22];
  const float* rey    = (const float*)d_in[23];
  const float* ley    = (const float*)d_in[24];
  const float* m_tmpl = (const float*)d_in[25];
  const float* m_sd   = (const float*)d_in[26];
  const float* m_pd   = (const float*)d_in[27];
  const float* m_jr   = (const float*)d_in[28];
  const float* m_W    = (const float*)d_in[29];
  const float* s_tmpl = (const float*)d_in[30];
  const float* s_sd   = (const float*)d_in[31];
  const float* s_pd   = (const float*)d_in[32];
  const float* s_jr   = (const float*)d_in[33];
  const float* s_W    = (const float*)d_in[34];
  // setup_inputs() dict order (NOT reference-signature order!):
  //   35: smplx2flame_ind (VF), 36: smplx2mano_left (VM),
  //   37: smplx2mano_right (VM), 38: head_index (3000)
  const int* s2f  = (const int*)d_in[35];
  const int* s2ml = (const int*)d_in[36];
  const int* s2mr = (const int*)d_in[37];
  const int* hidx = (const int*)d_in[38];
  float* outp = (float*)d_out;

  // newt (v_template/v_posed) lives in d_out; k_skin reads/writes in-place.
  float* newt = outp;

  float* w = (float*)d_ws;
  size_t o = 0;
  auto A_ = [&](size_t n){ size_t r = o; o += (n + 3) & ~(size_t)3; return r; };
  float* bTf  = w + A_((size_t)KSH*NB);
  float* bTs  = w + A_((size_t)KSH*NB);
  float* pTf  = w + A_((size_t)KPF*NB);
  float* pTl  = w + A_((size_t)KPM*NB);
  float* pTr  = w + A_((size_t)KPM*NB);
  float* pTs  = w + A_((size_t)KPS*NB);
  float* rot  = w + A_((size_t)NB*92*9);
  float* vshf = w + A_((size_t)NB*NF3v);
  float* Jf   = w + A_((size_t)NB*15);
  float* pJf  = w + A_((size_t)NB*15);
  float* Af   = w + A_((size_t)NB*60);
  float* vshm = w + A_((size_t)NM3v);
  float* Jm   = w + A_((size_t)48);
  float* Al   = w + A_((size_t)NB*192);
  float* Ar   = w + A_((size_t)NB*192);
  float* tbj  = w + A_((size_t)NB*165);
  float* As   = w + A_((size_t)NB*660);
  (void)ws_size; (void)n_in; (void)in_sizes; (void)out_size;

  // 1. prep: transposes + rodrigues
  {
    int total = 2*KSH*NB + 92*NB;
    k_prep<<<(total+255)/256, 256, 0, stream>>>(sp, fe, be, eye, jaw, lhp, rhp, gp, bp,
                                                bTf, bTs, rot, pTf, pTl, pTr, pTs);
  }
  // 2. smplx shape GEMM -> new_t (in d_out)
  k_gemm_shaped<<<(NS3v+63)/64, 256, 0, stream>>>(s_sd, bTs, s_tmpl, newt, NS3v, KSH);
  // 3. smplx joint regression (+joints_offset) -> tbj
  k_jreg<<<dim3(NB,5), 256, 0, stream>>>(s_jr, newt, joff, tbj, 55, VS, 11);
  // 4. flame shape GEMM -> vshf
  k_gemm_shaped<<<(NF3v+63)/64, 256, 0, stream>>>(f_sd, bTf, f_tmpl, vshf, NF3v, KSH);
  // 5. flame joint regression -> Jf
  k_jreg<<<dim3(NB,1), 256, 0, stream>>>(f_jr, vshf, nullptr, Jf, 5, VF, 5);
  // 6. mano shape (batch independent) -> vshm, Jm
  k_mano_shaped<<<1, 256, 0, stream>>>(m_tmpl, m_sd, mb, m_jr, vshm, Jm);
  // 7. FK all models -> Af, Al, Ar, As, pJf
  k_fk<<<dim3(NB,4), 64, 0, stream>>>(rot, Jf, Jm, tbj, Af, Al, Ar, As, pJf);
  // 8. flame pose GEMM in-place -> vshf becomes v_posed_f
  k_gemm_pose<<<(NF3v+63)/64, 256, 0, stream>>>(f_pd, pTf, vshf, NF3v, KPF);
  // 9. flame skin at head_index -> scatter into new_t
  k_head<<<dim3((NHD+255)/256, NB), 256, 0, stream>>>(vshf, Af, f_W, rey, ley, eyep,
                                                      hsc, hoff, pJf, tbj, hidx, s2f, newt);
  // 10. mano pose+skin both hands -> scatter into new_t
  k_mano_skin<<<dim3((VM+255)/256, NB, 2), 256, 0, stream>>>(vshm, m_pd, pTl, pTr, Al, Ar,
                                                             m_W, Jm, lsc, loff, rsc, roff,
                                                             tbj, s2ml, s2mr, newt);
  // 11. smplx pose GEMM in-place -> new_t becomes v_posed
  k_gemm_pose<<<(NS3v+63)/64, 256, 0, stream>>>(s_pd, pTs, newt, NS3v, KPS);
  // 12. final skin -> d_out (in-place over newt)
  k_skin<<<dim3((VS+SKV-1)/SKV, NB/4), 256, 0, stream>>>(s_W, As, newt, outp);
}

// Round 9
// 894.726 us; speedup vs baseline: 2.0052x; 1.1113x over previous
//
#include <hip/hip_runtime.h>
#include <math.h>

#define NB 128
#define VS 10475
#define VF 5023
#define VM 778
#define NS3v (VS*3)   // 31425
#define NF3v (VF*3)   // 15069
#define NM3v (VM*3)   // 2334
#define KSH 350
#define KPF 36
#define KPM 135
#define KPS 486
#define NHD 3000
#define JSPLIT 8

__device__ const int PAR_F[5]  = {-1,0,1,1,1};
__device__ const int PAR_M[16] = {-1,0,1,2,0,4,5,0,7,8,0,10,11,0,13,14};
__device__ const int PAR_S[55] = {-1,0,0,0,1,2,3,4,5,6,7,8,9,9,9,12,13,14,16,17,18,19,15,15,15,
                                  20,25,26,20,28,29,20,31,32,20,34,35,20,37,38,21,40,41,21,43,44,
                                  21,46,47,21,49,50,21,52,53};

// ---------------- prep: betas transposes + rodrigues + pf^T ----------------
__global__ __launch_bounds__(256) void k_prep(
    const float* __restrict__ sp, const float* __restrict__ fe, const float* __restrict__ be,
    const float* __restrict__ eye, const float* __restrict__ jaw,
    const float* __restrict__ lhp, const float* __restrict__ rhp,
    const float* __restrict__ gp, const float* __restrict__ bp,
    float* __restrict__ bTf, float* __restrict__ bTs,
    float* __restrict__ rot, float* __restrict__ pTf, float* __restrict__ pTl,
    float* __restrict__ pTr, float* __restrict__ pTs)
{
  int t = blockIdx.x*256 + threadIdx.x;
  if (t < 2*KSH*NB) {
    int which = t / (KSH*NB);
    int r = t % (KSH*NB);
    int l = r / NB, b = r % NB;
    float v;
    if (which==0) v = (l<300)? sp[b*300+l] : fe[b*50+(l-300)];
    else          v = (l<300)? sp[b*300+l] : be[b*50+(l-300)];
    if (which==0) bTf[l*NB+b] = v; else bTs[l*NB+b] = v;
    return;
  }
  t -= 2*KSH*NB;
  if (t >= 92*NB) return;
  int b = t / 92, jj = t % 92;
  int model, j;
  if (jj < 5)       { model=0; j=jj; }
  else if (jj < 21) { model=1; j=jj-5; }
  else if (jj < 37) { model=2; j=jj-21; }
  else              { model=3; j=jj-37; }
  float ax=0.f, ay=0.f, az=0.f;
  if (model==0) {
    if (j==2){ ax=jaw[b*3]; ay=jaw[b*3+1]; az=jaw[b*3+2]; }
    else if (j==3){ ax=eye[b*6]; ay=eye[b*6+1]; az=eye[b*6+2]; }
    else if (j==4){ ax=eye[b*6+3]; ay=eye[b*6+4]; az=eye[b*6+5]; }
  } else if (model==1) {
    if (j>0){ int o=(b*15+(j-1))*3; ax=lhp[o]; ay=lhp[o+1]; az=lhp[o+2]; }
  } else if (model==2) {
    if (j>0){ int o=(b*15+(j-1))*3; ax=rhp[o]; ay=rhp[o+1]; az=rhp[o+2]; }
  } else {
    if (j==0){ ax=gp[b*3]; ay=gp[b*3+1]; az=gp[b*3+2]; }
    else if (j<=21){ int o=(b*21+(j-1))*3; ax=bp[o]; ay=bp[o+1]; az=bp[o+2]; }
  }
  float a2 = ax*ax+ay*ay+az*az + 1e-8f;
  float ang = sqrtf(a2);
  float inv = 1.f/ang;
  float nx=ax*inv, ny=ay*inv, nz=az*inv;
  float s = sinf(ang), c = cosf(ang);
  float n2 = nx*nx+ny*ny+nz*nz;
  float oc = 1.f - c;
  float R[9];
  R[0] = 1.f + oc*(nx*nx - n2);
  R[1] = -s*nz + oc*(nx*ny);
  R[2] =  s*ny + oc*(nx*nz);
  R[3] =  s*nz + oc*(ny*nx);
  R[4] = 1.f + oc*(ny*ny - n2);
  R[5] = -s*nx + oc*(ny*nz);
  R[6] = -s*ny + oc*(nz*nx);
  R[7] =  s*nx + oc*(nz*ny);
  R[8] = 1.f + oc*(nz*nz - n2);
  float* rr = rot + ((size_t)(b*92+jj))*9;
  #pragma unroll
  for (int e=0;e<9;e++) rr[e]=R[e];
  if (j>0) {
    float* pT = (model==0)?pTf:(model==1)?pTl:(model==2)?pTr:pTs;
    int kbase = (j-1)*9;
    #pragma unroll
    for (int e=0;e<9;e++) {
      float v = R[e] - ((e==0||e==4||e==8)?1.f:0.f);
      pT[(kbase+e)*NB + b] = v;
    }
  }
}

// ---------------- GEMM: out[b][n] = tmpl[n] + sum_k S[n][k]*bT[k][b] -------
__global__ __launch_bounds__(256) void k_gemm_shaped(
    const float* __restrict__ S, const float* __restrict__ bT,
    const float* __restrict__ tmpl, float* __restrict__ out, int N, int K)
{
  __shared__ __align__(16) float sT[64*36];
  __shared__ __align__(16) float pfc[32*NB];
  int tid = threadIdx.x;
  int n0 = blockIdx.x*64;
  float acc[4][8];
  #pragma unroll
  for (int i=0;i<4;i++)
    #pragma unroll
    for (int jn=0;jn<8;jn++) acc[i][jn]=0.f;
  int bg = tid & 31, ng = tid >> 5;
  int b0 = bg*4, nl0 = ng*8;
  int nch = (K+31)>>5;
  for (int ch=0; ch<nch; ch++) {
    int k0 = ch*32;
    __syncthreads();
    { // stage S tile [64 rows][32 k], row-major in LDS (stride 36)
      int r = tid>>2, kq = (tid&3)*8;
      int n = n0 + r;
      #pragma unroll
      for (int i=0;i<8;i++) {
        int k = k0 + kq + i;
        float v = 0.f;
        if (n < N && k < K) v = S[(size_t)n*K + k];
        sT[r*36 + kq + i] = v;
      }
    }
    { // stage pf tile [32][128] — contiguous copy from (K,128) layout
      #pragma unroll
      for (int i=0;i<4;i++) {
        int f = tid + i*256;          // float4 index 0..1023
        int k = k0 + (f>>5);
        float4 v = make_float4(0.f,0.f,0.f,0.f);
        if (k < K) v = *(const float4*)(bT + (size_t)k0*NB + (size_t)f*4);
        *(float4*)(pfc + f*4) = v;
      }
    }
    __syncthreads();
    // unroll 2 (not full): full unroll invites hipcc to hoist all LDS
    // float4 loads -> register spill (observed on k_skin R7).
    #pragma unroll 2
    for (int kq=0; kq<8; kq++) {
      float4 p0 = *(const float4*)&pfc[(kq*4+0)*NB + b0];
      float4 p1 = *(const float4*)&pfc[(kq*4+1)*NB + b0];
      float4 p2 = *(const float4*)&pfc[(kq*4+2)*NB + b0];
      float4 p3 = *(const float4*)&pfc[(kq*4+3)*NB + b0];
      #pragma unroll
      for (int nn=0;nn<8;nn++) {
        float4 s4 = *(const float4*)&sT[(nl0+nn)*36 + kq*4];
        acc[0][nn] += p0.x*s4.x + p1.x*s4.y + p2.x*s4.z + p3.x*s4.w;
        acc[1][nn] += p0.y*s4.x + p1.y*s4.y + p2.y*s4.z + p3.y*s4.w;
        acc[2][nn] += p0.z*s4.x + p1.z*s4.y + p2.z*s4.z + p3.z*s4.w;
        acc[3][nn] += p0.w*s4.x + p1.w*s4.y + p2.w*s4.z + p3.w*s4.w;
      }
    }
  }
  #pragma unroll
  for (int bi=0; bi<4; bi++) {
    int b = b0 + bi;
    #pragma unroll
    for (int nn=0; nn<8; nn++) {
      int n = n0 + nl0 + nn;
      if (n < N) out[(size_t)b*N + n] = tmpl[n] + acc[bi][nn];
    }
  }
}

// ------- GEMM (k-major S): out[b][n] += sum_k S[k][n]*pT[k][b] (in-place) --
__global__ __launch_bounds__(256) void k_gemm_pose(
    const float* __restrict__ S, const float* __restrict__ pT,
    float* __restrict__ out, int N, int K)
{
  __shared__ __align__(16) float sK[32*68];
  __shared__ __align__(16) float pfc[32*NB];
  int tid = threadIdx.x;
  int n0 = blockIdx.x*64;
  float acc[4][8];
  #pragma unroll
  for (int i=0;i<4;i++)
    #pragma unroll
    for (int jn=0;jn<8;jn++) acc[i][jn]=0.f;
  int bg = tid & 31, ng = tid >> 5;
  int b0 = bg*4, nl0 = ng*8;
  int nch = (K+31)>>5;
  for (int ch=0; ch<nch; ch++) {
    int k0 = ch*32;
    __syncthreads();
    { // stage S tile [32 k][64 n] (stride 68)
      int kl = tid>>3;
      int k = k0 + kl;
      int cc = (tid&7)*8;
      #pragma unroll
      for (int i=0;i<8;i++) {
        int n = n0 + cc + i;
        float v = 0.f;
        if (k < K && n < N) v = S[(size_t)k*N + n];
        sK[kl*68 + cc + i] = v;
      }
    }
    {
      #pragma unroll
      for (int i=0;i<4;i++) {
        int f = tid + i*256;
        int k = k0 + (f>>5);
        float4 v = make_float4(0.f,0.f,0.f,0.f);
        if (k < K) v = *(const float4*)(pT + (size_t)k0*NB + (size_t)f*4);
        *(float4*)(pfc + f*4) = v;
      }
    }
    __syncthreads();
    #pragma unroll 2
    for (int kq=0; kq<8; kq++) {
      float4 pv[4];
      #pragma unroll
      for (int kk=0;kk<4;kk++) pv[kk] = *(const float4*)&pfc[(kq*4+kk)*NB + b0];
      #pragma unroll
      for (int kk=0;kk<4;kk++) {
        float4 A4 = *(const float4*)&sK[(kq*4+kk)*68 + nl0];
        float4 B4 = *(const float4*)&sK[(kq*4+kk)*68 + nl0 + 4];
        float sv[8] = {A4.x,A4.y,A4.z,A4.w,B4.x,B4.y,B4.z,B4.w};
        float4 p = pv[kk];
        #pragma unroll
        for (int nn=0;nn<8;nn++) {
          acc[0][nn] += p.x*sv[nn];
          acc[1][nn] += p.y*sv[nn];
          acc[2][nn] += p.z*sv[nn];
          acc[3][nn] += p.w*sv[nn];
        }
      }
    }
  }
  #pragma unroll
  for (int bi=0; bi<4; bi++) {
    int b = b0 + bi;
    #pragma unroll
    for (int nn=0; nn<8; nn++) {
      int n = n0 + nl0 + nn;
      if (n < N) out[(size_t)b*N + n] += acc[bi][nn];
    }
  }
}

// -------- joint regression, split-V partials ------------------------------
// R8: single-block-per-(b,jg) k_jreg was latency-bound (186 us, VALUBusy 4.6%,
// occupancy 29%, hbm 1.2%). Split V across blockIdx.z (JSPLIT=8) -> 8x blocks,
// then reduce partials in a tiny second kernel.
__global__ __launch_bounds__(256) void k_jreg_part(
    const float* __restrict__ Jreg, const float* __restrict__ vsh,
    float* __restrict__ part, int NJ, int V, int JG, int NGY)
{
  int b = blockIdx.x;
  int gy = blockIdx.y;
  int jg0 = gy * JG;
  int sp = blockIdx.z;
  int tid = threadIdx.x;
  int vlo = (int)(((long long)V * sp) / JSPLIT);
  int vhi = (int)(((long long)V * (sp+1)) / JSPLIT);
  float acc[11][3];
  #pragma unroll
  for (int jl=0;jl<11;jl++){ acc[jl][0]=0.f; acc[jl][1]=0.f; acc[jl][2]=0.f; }
  const float* vb = vsh + (size_t)b*V*3;
  for (int v=vlo+tid; v<vhi; v+=256) {
    float x0 = vb[3*v], x1 = vb[3*v+1], x2 = vb[3*v+2];
    #pragma unroll
    for (int jl=0;jl<11;jl++) {
      if (jl < JG && jg0+jl < NJ) {
        float w = Jreg[(size_t)(jg0+jl)*V + v];
        acc[jl][0] += w*x0; acc[jl][1] += w*x1; acc[jl][2] += w*x2;
      }
    }
  }
  #pragma unroll
  for (int jl=0;jl<11;jl++)
    #pragma unroll
    for (int c=0;c<3;c++)
      #pragma unroll
      for (int off=32; off; off>>=1)
        acc[jl][c] += __shfl_down(acc[jl][c], off, 64);
  __shared__ float red[4][33];
  int wave = tid>>6, lane = tid&63;
  if (lane==0) {
    #pragma unroll
    for (int jl=0;jl<11;jl++)
      #pragma unroll
      for (int c=0;c<3;c++) red[wave][jl*3+c] = acc[jl][c];
  }
  __syncthreads();
  if (tid < 33) {
    int jl = tid/3;
    if (jl < JG && jg0+jl < NJ) {
      float sum = red[0][tid]+red[1][tid]+red[2][tid]+red[3][tid];
      part[(((size_t)b*NGY + gy)*JSPLIT + sp)*33 + tid] = sum;
    }
  }
}

__global__ __launch_bounds__(256) void k_jreg_reduce(
    const float* __restrict__ part, const float* __restrict__ joff,
    float* __restrict__ out, int NJ, int JG, int NGY)
{
  int i = blockIdx.x*256 + threadIdx.x;
  if (i >= NB*NJ*3) return;
  int b = i/(NJ*3);
  int rem = i%(NJ*3);
  int j = rem/3, c = rem%3;
  int gy = j/JG, jl = j%JG;
  float s = 0.f;
  #pragma unroll
  for (int sp=0; sp<JSPLIT; sp++)
    s += part[(((size_t)b*NGY + gy)*JSPLIT + sp)*33 + jl*3 + c];
  if (joff) s += joff[i];
  out[i] = s;
}

// ---------------- mano shape (batch-independent) ---------------------------
__global__ __launch_bounds__(256) void k_mano_shaped(
    const float* __restrict__ tmpl, const float* __restrict__ sdirs,
    const float* __restrict__ mb_, const float* __restrict__ Jreg,
    float* __restrict__ vsh, float* __restrict__ Jm)
{
  __shared__ float vs[NM3v];
  __shared__ float mb[10];
  int tid = threadIdx.x;
  if (tid<10) mb[tid]=mb_[tid];
  __syncthreads();
  for (int n=tid; n<NM3v; n+=256) {
    float a = tmpl[n];
    #pragma unroll
    for (int l=0;l<10;l++) a += sdirs[n*10+l]*mb[l];
    vs[n]=a; vsh[n]=a;
  }
  __syncthreads();
  if (tid<48) {
    int j=tid/3, c=tid%3;
    float s=0.f;
    for (int v=0;v<VM;v++) s += Jreg[j*VM+v]*vs[v*3+c];
    Jm[tid]=s;
  }
}

// ---------------- forward kinematics (all 4 models) ------------------------
__global__ __launch_bounds__(64) void k_fk(
    const float* __restrict__ rot_all, const float* __restrict__ Jf,
    const float* __restrict__ Jm, const float* __restrict__ tbj,
    float* __restrict__ Af, float* __restrict__ Al, float* __restrict__ Ar,
    float* __restrict__ As, float* __restrict__ pJf)
{
  int b = blockIdx.x;
  int model = blockIdx.y;
  int NJ, roff; const int* par; const float* J; float* A;
  if (model==0){ NJ=5;  roff=0;  par=PAR_F; J=Jf + (size_t)b*15;  A=Af + (size_t)b*60;  }
  else if (model==1){ NJ=16; roff=5;  par=PAR_M; J=Jm;            A=Al + (size_t)b*192; }
  else if (model==2){ NJ=16; roff=21; par=PAR_M; J=Jm;            A=Ar + (size_t)b*192; }
  else { NJ=55; roff=37; par=PAR_S; J=tbj + (size_t)b*165; A=As + (size_t)b*660; }
  const float* rb = rot_all + ((size_t)(b*92 + roff))*9;
  __shared__ float ch[55*12];
  __shared__ float JL[55*3];
  int tid = threadIdx.x;
  for (int i=tid;i<NJ*3;i+=64) JL[i]=J[i];
  __syncthreads();
  for (int j=0;j<NJ;j++) {
    if (tid<12) {
      int m=tid>>2, nn=tid&3;
      float v;
      if (j==0) v = (nn<3)? rb[m*3+nn] : JL[m];
      else {
        int p = par[j];
        const float* Rj = rb + j*9;
        float t0,t1,t2;
        if (nn<3){ t0=Rj[nn]; t1=Rj[3+nn]; t2=Rj[6+nn]; }
        else { t0=JL[j*3]-JL[p*3]; t1=JL[j*3+1]-JL[p*3+1]; t2=JL[j*3+2]-JL[p*3+2]; }
        const float* cp = ch + p*12 + m*4;
        v = cp[0]*t0 + cp[1]*t1 + cp[2]*t2;
        if (nn==3) v += cp[3];
      }
      ch[j*12+tid] = v;
    }
    __syncthreads();
  }
  if (model==0 && tid < 15) {
    int j=tid/3, c=tid%3;
    pJf[(size_t)b*15 + tid] = ch[j*12 + c*4 + 3];
  }
  for (int i=tid; i<NJ*12; i+=64) {
    int j=i/12, e=i%12, m=e>>2, nn=e&3;
    float v = ch[i];
    if (nn==3) {
      const float* cj = ch + j*12 + m*4;
      v -= cj[0]*JL[j*3] + cj[1]*JL[j*3+1] + cj[2]*JL[j*3+2];
    }
    A[i] = v;
  }
}

// ---------------- flame skin at head_index + scatter into new_t ------------
__global__ __launch_bounds__(256) void k_head(
    const float* __restrict__ vpf, const float* __restrict__ Af,
    const float* __restrict__ Wf, const float* __restrict__ rey,
    const float* __restrict__ ley, const float* __restrict__ eyep,
    const float* __restrict__ hscale, const float* __restrict__ hoff,
    const float* __restrict__ pJf, const float* __restrict__ tbj,
    const int* __restrict__ hidx, const int* __restrict__ s2f,
    float* __restrict__ new_t)
{
  int b = blockIdx.y;
  int i = blockIdx.x*256 + threadIdx.x;
  __shared__ float AL[60];
  __shared__ float mm[3];
  if (threadIdx.x < 60) AL[threadIdx.x] = Af[(size_t)b*60 + threadIdx.x];
  if (threadIdx.x < 3) {
    int c = threadIdx.x;
    float hm = 0.5f*(pJf[(size_t)b*15+9+c] + pJf[(size_t)b*15+12+c]);
    float tm = 0.5f*(tbj[(size_t)b*165 + 69 + c] + tbj[(size_t)b*165 + 72 + c]);
    mm[c] = tm - hm;
  }
  __syncthreads();
  if (i >= NHD) return;
  int v = hidx[i];
  float w[5];
  #pragma unroll
  for (int j=0;j<5;j++) w[j] = Wf[v*5+j];
  float T[12];
  #pragma unroll
  for (int e=0;e<12;e++){
    float s=0.f;
    #pragma unroll
    for (int j=0;j<5;j++) s += w[j]*AL[j*12+e];
    T[e]=s;
  }
  const float* vp = vpf + (size_t)b*NF3v + 3*v;
  float x0=vp[0], x1=vp[1], x2=vp[2];
  float el0 = eyep[b*2], el1 = eyep[b*2+1];
  float hs = hscale[b];
  int col = s2f[v];
  float* dst = new_t + (size_t)b*NS3v + 3*col;
  #pragma unroll
  for (int c=0;c<3;c++){
    float r = T[c*4]*x0 + T[c*4+1]*x1 + T[c*4+2]*x2 + T[c*4+3];
    r += rey[3*v+c]*el1 + ley[3*v+c]*el0;
    r = r*hs + hoff[b*3+c];
    dst[c] = r + mm[c];
  }
}

// ---------------- mano pose+skin + scatter into new_t ----------------------
__global__ __launch_bounds__(256) void k_mano_skin(
    const float* __restrict__ vshm, const float* __restrict__ pdirs,
    const float* __restrict__ pTl, const float* __restrict__ pTr,
    const float* __restrict__ Al, const float* __restrict__ Ar,
    const float* __restrict__ Wm, const float* __restrict__ Jm,
    const float* __restrict__ lsc, const float* __restrict__ loffp,
    const float* __restrict__ rsc, const float* __restrict__ roffp,
    const float* __restrict__ tbj,
    const int* __restrict__ s2ml, const int* __restrict__ s2mr,
    float* __restrict__ new_t)
{
  int hand = blockIdx.z;
  int b = blockIdx.y;
  int v = blockIdx.x*256 + threadIdx.x;
  const float* pT = hand? pTr : pTl;
  const float* A  = (hand? Ar : Al) + (size_t)b*192;
  __shared__ float AL[192];
  __shared__ float PF[KPM];
  if (threadIdx.x < 192) AL[threadIdx.x] = A[threadIdx.x];
  if (threadIdx.x >= 192 && threadIdx.x < 192+64) {
    for (int k = threadIdx.x - 192; k < KPM; k += 64) PF[k] = pT[k*NB + b];
  }
  __syncthreads();
  if (v >= VM) return;
  float vp0=vshm[3*v], vp1=vshm[3*v+1], vp2=vshm[3*v+2];
  for (int k=0;k<KPM;k++) {
    float p = PF[k];
    vp0 += p * pdirs[(size_t)k*NM3v + 3*v];
    vp1 += p * pdirs[(size_t)k*NM3v + 3*v+1];
    vp2 += p * pdirs[(size_t)k*NM3v + 3*v+2];
  }
  float T[12];
  #pragma unroll
  for (int e=0;e<12;e++) T[e]=0.f;
  for (int j=0;j<16;j++){
    float w = Wm[v*16+j];
    #pragma unroll
    for (int e=0;e<12;e++) T[e] += w*AL[j*12+e];
  }
  float sc = hand? rsc[b] : lsc[b];
  const float* of = hand? (roffp+b*3) : (loffp+b*3);
  const float* tb = tbj + (size_t)b*165 + (hand?21:20)*3;
  int col = (hand? s2mr : s2ml)[v];
  float* dst = new_t + (size_t)b*NS3v + 3*col;
  #pragma unroll
  for (int c=0;c<3;c++){
    float r = T[c*4]*vp0 + T[c*4+1]*vp1 + T[c*4+2]*vp2 + T[c*4+3];
    r = r*sc + of[c];
    r = r - Jm[c];
    if (hand==0 && c==0) r = -r;
    dst[c] = r + tb[c];
  }
}

// ---------------- final 55-joint skin --------------------------------------
// R7 fix: unroll 1 on jq kills LDS-load hoist (was VGPR=256 + 1.7 GB spill);
// 2 v/thread + SKV=128 -> LDS 41.5 KB (3 blocks/CU). 805 us -> off top-5.
#define SKV 128
__global__ __launch_bounds__(256) void k_skin(
    const float* __restrict__ W, const float* __restrict__ As,
    const float* __restrict__ vposed, float* __restrict__ outp)
{
  __shared__ __align__(16) float WL[SKV*60];   // 30720 B
  __shared__ __align__(16) float AL[4*672];    // 10752 B
  int tid = threadIdx.x;
  int v0 = blockIdx.x*SKV;
  int b0 = blockIdx.y*4;
  for (int i=tid; i<SKV*55; i+=256) {
    int vl = i/55, j = i%55;
    int v = v0+vl;
    WL[vl*60+j] = (v<VS)? W[(size_t)v*55+j] : 0.f;
  }
  for (int i=tid;i<SKV;i+=256) WL[i*60+55]=0.f;
  for (int i=tid; i<4*660; i+=256) {
    int bl = i/660, r = i%660;
    AL[bl*672 + r] = As[((size_t)(b0+bl))*660 + r];
  }
  if (tid < 48) {
    int bl=tid/12, e=tid%12;
    AL[bl*672 + 660 + e] = 0.f;
  }
  __syncthreads();
  int bl = tid>>6, lane = tid&63;
  int b = b0 + bl;
  const float* ALb = AL + bl*672;
  float T[2][12];
  #pragma unroll
  for (int q=0;q<2;q++)
    #pragma unroll
    for (int e=0;e<12;e++) T[q][e]=0.f;
  #pragma unroll 1
  for (int jq=0; jq<14; jq++) {
    float4 w40 = *(const float4*)&WL[lane*60 + jq*4];
    float4 w41 = *(const float4*)&WL[(lane+64)*60 + jq*4];
    #pragma unroll
    for (int jj=0;jj<4;jj++) {
      int j = jq*4+jj;
      float4 a0 = *(const float4*)&ALb[j*12];
      float4 a1 = *(const float4*)&ALb[j*12+4];
      float4 a2 = *(const float4*)&ALb[j*12+8];
      float w0 = (jj==0)?w40.x:(jj==1)?w40.y:(jj==2)?w40.z:w40.w;
      float w1 = (jj==0)?w41.x:(jj==1)?w41.y:(jj==2)?w41.z:w41.w;
      T[0][0]+=w0*a0.x; T[0][1]+=w0*a0.y; T[0][2] +=w0*a1.x; T[0][3] +=w0*a1.y;
      T[0][4]+=w0*a0.z; T[0][5]+=w0*a0.w; T[0][6] +=w0*a1.z; T[0][7] +=w0*a1.w;
      T[0][8]+=w0*a2.x; T[0][9]+=w0*a2.y; T[0][10]+=w0*a2.z; T[0][11]+=w0*a2.w;
      T[1][0]+=w1*a0.x; T[1][1]+=w1*a0.y; T[1][2] +=w1*a1.x; T[1][3] +=w1*a1.y;
      T[1][4]+=w1*a0.z; T[1][5]+=w1*a0.w; T[1][6] +=w1*a1.z; T[1][7] +=w1*a1.w;
      T[1][8]+=w1*a2.x; T[1][9]+=w1*a2.y; T[1][10]+=w1*a2.z; T[1][11]+=w1*a2.w;
    }
  }
  // T element mapping: [0]=A0,[1]=A1,[4]=A2,[5]=A3,[2]=A4,[3]=A5,[6]=A6,
  // [7]=A7,[8..11]=A8..A11 (un-permuted on apply below)
  #pragma unroll
  for (int q=0;q<2;q++) {
    int v = v0 + lane + 64*q;
    if (v < VS) {
      const float* vp = vposed + (size_t)b*NS3v + 3*v;
      float x0=vp[0], x1=vp[1], x2=vp[2];
      float* dst = outp + (size_t)b*NS3v + 3*v;
      dst[0] = T[q][0]*x0 + T[q][1]*x1 + T[q][4]*x2 + T[q][5];
      dst[1] = T[q][2]*x0 + T[q][3]*x1 + T[q][6]*x2 + T[q][7];
      dst[2] = T[q][8]*x0 + T[q][9]*x1 + T[q][10]*x2 + T[q][11];
    }
  }
}

extern "C" void kernel_launch(void* const* d_in, const int* in_sizes, int n_in,
                              void* d_out, int out_size, void* d_ws, size_t ws_size,
                              hipStream_t stream) {
  const float* sp   = (const float*)d_in[0];
  const float* fe   = (const float*)d_in[1];
  const float* eye  = (const float*)d_in[2];
  const float* jaw  = (const float*)d_in[3];
  const float* eyep = (const float*)d_in[4];
  const float* hsc  = (const float*)d_in[5];
  const float* hoff = (const float*)d_in[6];
  const float* lhp  = (const float*)d_in[7];
  const float* rhp  = (const float*)d_in[8];
  const float* lsc  = (const float*)d_in[9];
  const float* loff = (const float*)d_in[10];
  const float* rsc  = (const float*)d_in[11];
  const float* roff = (const float*)d_in[12];
  const float* be   = (const float*)d_in[13];
  const float* gp   = (const float*)d_in[14];
  const float* bp   = (const float*)d_in[15];
  const float* joff = (const float*)d_in[16];
  const float* mb   = (const float*)d_in[17];
  const float* f_tmpl = (const float*)d_in[18];
  const float* f_sd   = (const float*)d_in[19];
  const float* f_pd   = (const float*)d_in[20];
  const float* f_jr   = (const float*)d_in[21];
  const float* f_W    = (const float*)d_in[22];
  const float* rey    = (const float*)d_in[23];
  const float* ley    = (const float*)d_in[24];
  const float* m_tmpl = (const float*)d_in[25];
  const float* m_sd   = (const float*)d_in[26];
  const float* m_pd   = (const float*)d_in[27];
  const float* m_jr   = (const float*)d_in[28];
  const float* m_W    = (const float*)d_in[29];
  const float* s_tmpl = (const float*)d_in[30];
  const float* s_sd   = (const float*)d_in[31];
  const float* s_pd   = (const float*)d_in[32];
  const float* s_jr   = (const float*)d_in[33];
  const float* s_W    = (const float*)d_in[34];
  // setup_inputs() dict order (NOT reference-signature order!):
  //   35: smplx2flame_ind (VF), 36: smplx2mano_left (VM),
  //   37: smplx2mano_right (VM), 38: head_index (3000)
  const int* s2f  = (const int*)d_in[35];
  const int* s2ml = (const int*)d_in[36];
  const int* s2mr = (const int*)d_in[37];
  const int* hidx = (const int*)d_in[38];
  float* outp = (float*)d_out;

  // newt (v_template/v_posed) lives in d_out; k_skin reads/writes in-place.
  float* newt = outp;

  float* w = (float*)d_ws;
  size_t o = 0;
  auto A_ = [&](size_t n){ size_t r = o; o += (n + 3) & ~(size_t)3; return r; };
  float* bTf  = w + A_((size_t)KSH*NB);
  float* bTs  = w + A_((size_t)KSH*NB);
  float* pTf  = w + A_((size_t)KPF*NB);
  float* pTl  = w + A_((size_t)KPM*NB);
  float* pTr  = w + A_((size_t)KPM*NB);
  float* pTs  = w + A_((size_t)KPS*NB);
  float* rot  = w + A_((size_t)NB*92*9);
  float* vshf = w + A_((size_t)NB*NF3v);
  float* Jf   = w + A_((size_t)NB*15);
  float* pJf  = w + A_((size_t)NB*15);
  float* Af   = w + A_((size_t)NB*60);
  float* vshm = w + A_((size_t)NM3v);
  float* Jm   = w + A_((size_t)48);
  float* Al   = w + A_((size_t)NB*192);
  float* Ar   = w + A_((size_t)NB*192);
  float* tbj  = w + A_((size_t)NB*165);
  float* As   = w + A_((size_t)NB*660);
  float* partS = w + A_((size_t)NB*5*JSPLIT*33);
  float* partF = w + A_((size_t)NB*1*JSPLIT*33);
  (void)ws_size; (void)n_in; (void)in_sizes; (void)out_size;

  // 1. prep: transposes + rodrigues
  {
    int total = 2*KSH*NB + 92*NB;
    k_prep<<<(total+255)/256, 256, 0, stream>>>(sp, fe, be, eye, jaw, lhp, rhp, gp, bp,
                                                bTf, bTs, rot, pTf, pTl, pTr, pTs);
  }
  // 2. smplx shape GEMM -> new_t (in d_out)
  k_gemm_shaped<<<(NS3v+63)/64, 256, 0, stream>>>(s_sd, bTs, s_tmpl, newt, NS3v, KSH);
  // 3. smplx joint regression (+joints_offset) -> tbj  [split-V]
  k_jreg_part<<<dim3(NB,5,JSPLIT), 256, 0, stream>>>(s_jr, newt, partS, 55, VS, 11, 5);
  k_jreg_reduce<<<(NB*55*3+255)/256, 256, 0, stream>>>(partS, joff, tbj, 55, 11, 5);
  // 4. flame shape GEMM -> vshf
  k_gemm_shaped<<<(NF3v+63)/64, 256, 0, stream>>>(f_sd, bTf, f_tmpl, vshf, NF3v, KSH);
  // 5. flame joint regression -> Jf  [split-V]
  k_jreg_part<<<dim3(NB,1,JSPLIT), 256, 0, stream>>>(f_jr, vshf, partF, 5, VF, 5, 1);
  k_jreg_reduce<<<(NB*5*3+255)/256, 256, 0, stream>>>(partF, nullptr, Jf, 5, 5, 1);
  // 6. mano shape (batch independent) -> vshm, Jm
  k_mano_shaped<<<1, 256, 0, stream>>>(m_tmpl, m_sd, mb, m_jr, vshm, Jm);
  // 7. FK all models -> Af, Al, Ar, As, pJf
  k_fk<<<dim3(NB,4), 64, 0, stream>>>(rot, Jf, Jm, tbj, Af, Al, Ar, As, pJf);
  // 8. flame pose GEMM in-place -> vshf becomes v_posed_f
  k_gemm_pose<<<(NF3v+63)/64, 256, 0, stream>>>(f_pd, pTf, vshf, NF3v, KPF);
  // 9. flame skin at head_index -> scatter into new_t
  k_head<<<dim3((NHD+255)/256, NB), 256, 0, stream>>>(vshf, Af, f_W, rey, ley, eyep,
                                                      hsc, hoff, pJf, tbj, hidx, s2f, newt);
  // 10. mano pose+skin both hands -> scatter into new_t
  k_mano_skin<<<dim3((VM+255)/256, NB, 2), 256, 0, stream>>>(vshm, m_pd, pTl, pTr, Al, Ar,
                                                             m_W, Jm, lsc, loff, rsc, roff,
                                                             tbj, s2ml, s2mr, newt);
  // 11. smplx pose GEMM in-place -> new_t becomes v_posed
  k_gemm_pose<<<(NS3v+63)/64, 256, 0, stream>>>(s_pd, pTs, newt, NS3v, KPS);
  // 12. final skin -> d_out (in-place over newt)
  k_skin<<<dim3((VS+SKV-1)/SKV, NB/4), 256, 0, stream>>>(s_W, As, newt, outp);
}

// Round 10
// 746.991 us; speedup vs baseline: 2.4018x; 1.1978x over previous
//
#include <hip/hip_runtime.h>
#include <math.h>

#define NB 128
#define VS 10475
#define VF 5023
#define VM 778
#define NS3v (VS*3)   // 31425
#define NF3v (VF*3)   // 15069
#define NM3v (VM*3)   // 2334
#define KSH 350
#define KPF 36
#define KPM 135
#define KPS 486
#define NHD 3000
#define JSPLIT 8

__device__ const int PAR_F[5]  = {-1,0,1,1,1};
__device__ const int PAR_M[16] = {-1,0,1,2,0,4,5,0,7,8,0,10,11,0,13,14};
__device__ const int PAR_S[55] = {-1,0,0,0,1,2,3,4,5,6,7,8,9,9,9,12,13,14,16,17,18,19,15,15,15,
                                  20,25,26,20,28,29,20,31,32,20,34,35,20,37,38,21,40,41,21,43,44,
                                  21,46,47,21,49,50,21,52,53};

// ---------------- prep: betas transposes + rodrigues + pf^T ----------------
__global__ __launch_bounds__(256) void k_prep(
    const float* __restrict__ sp, const float* __restrict__ fe, const float* __restrict__ be,
    const float* __restrict__ eye, const float* __restrict__ jaw,
    const float* __restrict__ lhp, const float* __restrict__ rhp,
    const float* __restrict__ gp, const float* __restrict__ bp,
    float* __restrict__ bTf, float* __restrict__ bTs,
    float* __restrict__ rot, float* __restrict__ pTf, float* __restrict__ pTl,
    float* __restrict__ pTr, float* __restrict__ pTs)
{
  int t = blockIdx.x*256 + threadIdx.x;
  if (t < 2*KSH*NB) {
    int which = t / (KSH*NB);
    int r = t % (KSH*NB);
    int l = r / NB, b = r % NB;
    float v;
    if (which==0) v = (l<300)? sp[b*300+l] : fe[b*50+(l-300)];
    else          v = (l<300)? sp[b*300+l] : be[b*50+(l-300)];
    if (which==0) bTf[l*NB+b] = v; else bTs[l*NB+b] = v;
    return;
  }
  t -= 2*KSH*NB;
  if (t >= 92*NB) return;
  int b = t / 92, jj = t % 92;
  int model, j;
  if (jj < 5)       { model=0; j=jj; }
  else if (jj < 21) { model=1; j=jj-5; }
  else if (jj < 37) { model=2; j=jj-21; }
  else              { model=3; j=jj-37; }
  float ax=0.f, ay=0.f, az=0.f;
  if (model==0) {
    if (j==2){ ax=jaw[b*3]; ay=jaw[b*3+1]; az=jaw[b*3+2]; }
    else if (j==3){ ax=eye[b*6]; ay=eye[b*6+1]; az=eye[b*6+2]; }
    else if (j==4){ ax=eye[b*6+3]; ay=eye[b*6+4]; az=eye[b*6+5]; }
  } else if (model==1) {
    if (j>0){ int o=(b*15+(j-1))*3; ax=lhp[o]; ay=lhp[o+1]; az=lhp[o+2]; }
  } else if (model==2) {
    if (j>0){ int o=(b*15+(j-1))*3; ax=rhp[o]; ay=rhp[o+1]; az=rhp[o+2]; }
  } else {
    if (j==0){ ax=gp[b*3]; ay=gp[b*3+1]; az=gp[b*3+2]; }
    else if (j<=21){ int o=(b*21+(j-1))*3; ax=bp[o]; ay=bp[o+1]; az=bp[o+2]; }
  }
  float a2 = ax*ax+ay*ay+az*az + 1e-8f;
  float ang = sqrtf(a2);
  float inv = 1.f/ang;
  float nx=ax*inv, ny=ay*inv, nz=az*inv;
  float s = sinf(ang), c = cosf(ang);
  float n2 = nx*nx+ny*ny+nz*nz;
  float oc = 1.f - c;
  float R[9];
  R[0] = 1.f + oc*(nx*nx - n2);
  R[1] = -s*nz + oc*(nx*ny);
  R[2] =  s*ny + oc*(nx*nz);
  R[3] =  s*nz + oc*(ny*nx);
  R[4] = 1.f + oc*(ny*ny - n2);
  R[5] = -s*nx + oc*(ny*nz);
  R[6] = -s*ny + oc*(nz*nx);
  R[7] =  s*nx + oc*(nz*ny);
  R[8] = 1.f + oc*(nz*nz - n2);
  float* rr = rot + ((size_t)(b*92+jj))*9;
  #pragma unroll
  for (int e=0;e<9;e++) rr[e]=R[e];
  if (j>0) {
    float* pT = (model==0)?pTf:(model==1)?pTl:(model==2)?pTr:pTs;
    int kbase = (j-1)*9;
    #pragma unroll
    for (int e=0;e<9;e++) {
      float v = R[e] - ((e==0||e==4||e==8)?1.f:0.f);
      pT[(kbase+e)*NB + b] = v;
    }
  }
}

// ---------------- GEMM: out[b][n] = tmpl[n] + sum_k S[n][k]*bT[k][b] -------
__global__ __launch_bounds__(256) void k_gemm_shaped(
    const float* __restrict__ S, const float* __restrict__ bT,
    const float* __restrict__ tmpl, float* __restrict__ out, int N, int K)
{
  __shared__ __align__(16) float sT[64*36];
  __shared__ __align__(16) float pfc[32*NB];
  int tid = threadIdx.x;
  int n0 = blockIdx.x*64;
  float acc[4][8];
  #pragma unroll
  for (int i=0;i<4;i++)
    #pragma unroll
    for (int jn=0;jn<8;jn++) acc[i][jn]=0.f;
  int bg = tid & 31, ng = tid >> 5;
  int b0 = bg*4, nl0 = ng*8;
  int nch = (K+31)>>5;
  for (int ch=0; ch<nch; ch++) {
    int k0 = ch*32;
    __syncthreads();
    { // stage S tile [64 rows][32 k], row-major in LDS (stride 36)
      int r = tid>>2, kq = (tid&3)*8;
      int n = n0 + r;
      #pragma unroll
      for (int i=0;i<8;i++) {
        int k = k0 + kq + i;
        float v = 0.f;
        if (n < N && k < K) v = S[(size_t)n*K + k];
        sT[r*36 + kq + i] = v;
      }
    }
    { // stage pf tile [32][128] — contiguous copy from (K,128) layout
      #pragma unroll
      for (int i=0;i<4;i++) {
        int f = tid + i*256;          // float4 index 0..1023
        int k = k0 + (f>>5);
        float4 v = make_float4(0.f,0.f,0.f,0.f);
        if (k < K) v = *(const float4*)(bT + (size_t)k0*NB + (size_t)f*4);
        *(float4*)(pfc + f*4) = v;
      }
    }
    __syncthreads();
    // unroll 2 (not full): full unroll invites hipcc to hoist all LDS
    // float4 loads -> register spill (observed on k_skin R7).
    #pragma unroll 2
    for (int kq=0; kq<8; kq++) {
      float4 p0 = *(const float4*)&pfc[(kq*4+0)*NB + b0];
      float4 p1 = *(const float4*)&pfc[(kq*4+1)*NB + b0];
      float4 p2 = *(const float4*)&pfc[(kq*4+2)*NB + b0];
      float4 p3 = *(const float4*)&pfc[(kq*4+3)*NB + b0];
      #pragma unroll
      for (int nn=0;nn<8;nn++) {
        float4 s4 = *(const float4*)&sT[(nl0+nn)*36 + kq*4];
        acc[0][nn] += p0.x*s4.x + p1.x*s4.y + p2.x*s4.z + p3.x*s4.w;
        acc[1][nn] += p0.y*s4.x + p1.y*s4.y + p2.y*s4.z + p3.y*s4.w;
        acc[2][nn] += p0.z*s4.x + p1.z*s4.y + p2.z*s4.z + p3.z*s4.w;
        acc[3][nn] += p0.w*s4.x + p1.w*s4.y + p2.w*s4.z + p3.w*s4.w;
      }
    }
  }
  #pragma unroll
  for (int bi=0; bi<4; bi++) {
    int b = b0 + bi;
    #pragma unroll
    for (int nn=0; nn<8; nn++) {
      int n = n0 + nl0 + nn;
      if (n < N) out[(size_t)b*N + n] = tmpl[n] + acc[bi][nn];
    }
  }
}

// ------- GEMM (k-major S): out[b][n] += sum_k S[k][n]*pT[k][b] (in-place) --
__global__ __launch_bounds__(256) void k_gemm_pose(
    const float* __restrict__ S, const float* __restrict__ pT,
    float* __restrict__ out, int N, int K)
{
  __shared__ __align__(16) float sK[32*68];
  __shared__ __align__(16) float pfc[32*NB];
  int tid = threadIdx.x;
  int n0 = blockIdx.x*64;
  float acc[4][8];
  #pragma unroll
  for (int i=0;i<4;i++)
    #pragma unroll
    for (int jn=0;jn<8;jn++) acc[i][jn]=0.f;
  int bg = tid & 31, ng = tid >> 5;
  int b0 = bg*4, nl0 = ng*8;
  int nch = (K+31)>>5;
  for (int ch=0; ch<nch; ch++) {
    int k0 = ch*32;
    __syncthreads();
    { // stage S tile [32 k][64 n] (stride 68)
      int kl = tid>>3;
      int k = k0 + kl;
      int cc = (tid&7)*8;
      #pragma unroll
      for (int i=0;i<8;i++) {
        int n = n0 + cc + i;
        float v = 0.f;
        if (k < K && n < N) v = S[(size_t)k*N + n];
        sK[kl*68 + cc + i] = v;
      }
    }
    {
      #pragma unroll
      for (int i=0;i<4;i++) {
        int f = tid + i*256;
        int k = k0 + (f>>5);
        float4 v = make_float4(0.f,0.f,0.f,0.f);
        if (k < K) v = *(const float4*)(pT + (size_t)k0*NB + (size_t)f*4);
        *(float4*)(pfc + f*4) = v;
      }
    }
    __syncthreads();
    #pragma unroll 2
    for (int kq=0; kq<8; kq++) {
      float4 pv[4];
      #pragma unroll
      for (int kk=0;kk<4;kk++) pv[kk] = *(const float4*)&pfc[(kq*4+kk)*NB + b0];
      #pragma unroll
      for (int kk=0;kk<4;kk++) {
        float4 A4 = *(const float4*)&sK[(kq*4+kk)*68 + nl0];
        float4 B4 = *(const float4*)&sK[(kq*4+kk)*68 + nl0 + 4];
        float sv[8] = {A4.x,A4.y,A4.z,A4.w,B4.x,B4.y,B4.z,B4.w};
        float4 p = pv[kk];
        #pragma unroll
        for (int nn=0;nn<8;nn++) {
          acc[0][nn] += p.x*sv[nn];
          acc[1][nn] += p.y*sv[nn];
          acc[2][nn] += p.z*sv[nn];
          acc[3][nn] += p.w*sv[nn];
        }
      }
    }
  }
  #pragma unroll
  for (int bi=0; bi<4; bi++) {
    int b = b0 + bi;
    #pragma unroll
    for (int nn=0; nn<8; nn++) {
      int n = n0 + nl0 + nn;
      if (n < N) out[(size_t)b*N + n] += acc[bi][nn];
    }
  }
}

// -------- joint regression, split-V partials (R8 fix) ---------------------
__global__ __launch_bounds__(256) void k_jreg_part(
    const float* __restrict__ Jreg, const float* __restrict__ vsh,
    float* __restrict__ part, int NJ, int V, int JG, int NGY)
{
  int b = blockIdx.x;
  int gy = blockIdx.y;
  int jg0 = gy * JG;
  int sp = blockIdx.z;
  int tid = threadIdx.x;
  int vlo = (int)(((long long)V * sp) / JSPLIT);
  int vhi = (int)(((long long)V * (sp+1)) / JSPLIT);
  float acc[11][3];
  #pragma unroll
  for (int jl=0;jl<11;jl++){ acc[jl][0]=0.f; acc[jl][1]=0.f; acc[jl][2]=0.f; }
  const float* vb = vsh + (size_t)b*V*3;
  for (int v=vlo+tid; v<vhi; v+=256) {
    float x0 = vb[3*v], x1 = vb[3*v+1], x2 = vb[3*v+2];
    #pragma unroll
    for (int jl=0;jl<11;jl++) {
      if (jl < JG && jg0+jl < NJ) {
        float w = Jreg[(size_t)(jg0+jl)*V + v];
        acc[jl][0] += w*x0; acc[jl][1] += w*x1; acc[jl][2] += w*x2;
      }
    }
  }
  #pragma unroll
  for (int jl=0;jl<11;jl++)
    #pragma unroll
    for (int c=0;c<3;c++)
      #pragma unroll
      for (int off=32; off; off>>=1)
        acc[jl][c] += __shfl_down(acc[jl][c], off, 64);
  __shared__ float red[4][33];
  int wave = tid>>6, lane = tid&63;
  if (lane==0) {
    #pragma unroll
    for (int jl=0;jl<11;jl++)
      #pragma unroll
      for (int c=0;c<3;c++) red[wave][jl*3+c] = acc[jl][c];
  }
  __syncthreads();
  if (tid < 33) {
    int jl = tid/3;
    if (jl < JG && jg0+jl < NJ) {
      float sum = red[0][tid]+red[1][tid]+red[2][tid]+red[3][tid];
      part[(((size_t)b*NGY + gy)*JSPLIT + sp)*33 + tid] = sum;
    }
  }
}

__global__ __launch_bounds__(256) void k_jreg_reduce(
    const float* __restrict__ part, const float* __restrict__ joff,
    float* __restrict__ out, int NJ, int JG, int NGY)
{
  int i = blockIdx.x*256 + threadIdx.x;
  if (i >= NB*NJ*3) return;
  int b = i/(NJ*3);
  int rem = i%(NJ*3);
  int j = rem/3, c = rem%3;
  int gy = j/JG, jl = j%JG;
  float s = 0.f;
  #pragma unroll
  for (int sp=0; sp<JSPLIT; sp++)
    s += part[(((size_t)b*NGY + gy)*JSPLIT + sp)*33 + jl*3 + c];
  if (joff) s += joff[i];
  out[i] = s;
}

// ---------------- mano shape (batch-independent), parallelized -------------
// R9: old single-block k_mano_shaped was 161 us (occupancy 0.013%, 48-thread
// 778-iter serial jreg tail). Split: grid-parallel shape blend + one block
// per joint reduction.
__global__ __launch_bounds__(256) void k_mano_sh(
    const float* __restrict__ tmpl, const float* __restrict__ sdirs,
    const float* __restrict__ mb_, float* __restrict__ vsh)
{
  int n = blockIdx.x*256 + threadIdx.x;
  if (n >= NM3v) return;
  float a = tmpl[n];
  #pragma unroll
  for (int l=0;l<10;l++) a += sdirs[n*10+l]*mb_[l];
  vsh[n]=a;
}

__global__ __launch_bounds__(256) void k_mano_jreg(
    const float* __restrict__ Jreg, const float* __restrict__ vsh,
    float* __restrict__ Jm)
{
  int j = blockIdx.x;           // 16 joints
  int tid = threadIdx.x;
  float a0=0.f, a1=0.f, a2=0.f;
  for (int v=tid; v<VM; v+=256) {
    float w = Jreg[j*VM+v];
    a0 += w*vsh[3*v]; a1 += w*vsh[3*v+1]; a2 += w*vsh[3*v+2];
  }
  #pragma unroll
  for (int off=32; off; off>>=1) {
    a0 += __shfl_down(a0, off, 64);
    a1 += __shfl_down(a1, off, 64);
    a2 += __shfl_down(a2, off, 64);
  }
  __shared__ float red[4][3];
  int wave = tid>>6, lane = tid&63;
  if (lane==0){ red[wave][0]=a0; red[wave][1]=a1; red[wave][2]=a2; }
  __syncthreads();
  if (tid < 3)
    Jm[j*3+tid] = red[0][tid]+red[1][tid]+red[2][tid]+red[3][tid];
}

// ---------------- forward kinematics (all 4 models) ------------------------
__global__ __launch_bounds__(64) void k_fk(
    const float* __restrict__ rot_all, const float* __restrict__ Jf,
    const float* __restrict__ Jm, const float* __restrict__ tbj,
    float* __restrict__ Af, float* __restrict__ Al, float* __restrict__ Ar,
    float* __restrict__ As, float* __restrict__ pJf)
{
  int b = blockIdx.x;
  int model = blockIdx.y;
  int NJ, roff; const int* par; const float* J; float* A;
  if (model==0){ NJ=5;  roff=0;  par=PAR_F; J=Jf + (size_t)b*15;  A=Af + (size_t)b*60;  }
  else if (model==1){ NJ=16; roff=5;  par=PAR_M; J=Jm;            A=Al + (size_t)b*192; }
  else if (model==2){ NJ=16; roff=21; par=PAR_M; J=Jm;            A=Ar + (size_t)b*192; }
  else { NJ=55; roff=37; par=PAR_S; J=tbj + (size_t)b*165; A=As + (size_t)b*660; }
  const float* rb = rot_all + ((size_t)(b*92 + roff))*9;
  __shared__ float ch[55*12];
  __shared__ float JL[55*3];
  int tid = threadIdx.x;
  for (int i=tid;i<NJ*3;i+=64) JL[i]=J[i];
  __syncthreads();
  for (int j=0;j<NJ;j++) {
    if (tid<12) {
      int m=tid>>2, nn=tid&3;
      float v;
      if (j==0) v = (nn<3)? rb[m*3+nn] : JL[m];
      else {
        int p = par[j];
        const float* Rj = rb + j*9;
        float t0,t1,t2;
        if (nn<3){ t0=Rj[nn]; t1=Rj[3+nn]; t2=Rj[6+nn]; }
        else { t0=JL[j*3]-JL[p*3]; t1=JL[j*3+1]-JL[p*3+1]; t2=JL[j*3+2]-JL[p*3+2]; }
        const float* cp = ch + p*12 + m*4;
        v = cp[0]*t0 + cp[1]*t1 + cp[2]*t2;
        if (nn==3) v += cp[3];
      }
      ch[j*12+tid] = v;
    }
    __syncthreads();
  }
  if (model==0 && tid < 15) {
    int j=tid/3, c=tid%3;
    pJf[(size_t)b*15 + tid] = ch[j*12 + c*4 + 3];
  }
  for (int i=tid; i<NJ*12; i+=64) {
    int j=i/12, e=i%12, m=e>>2, nn=e&3;
    float v = ch[i];
    if (nn==3) {
      const float* cj = ch + j*12 + m*4;
      v -= cj[0]*JL[j*3] + cj[1]*JL[j*3+1] + cj[2]*JL[j*3+2];
    }
    A[i] = v;
  }
}

// ---------------- flame skin at head_index + scatter into new_t ------------
__global__ __launch_bounds__(256) void k_head(
    const float* __restrict__ vpf, const float* __restrict__ Af,
    const float* __restrict__ Wf, const float* __restrict__ rey,
    const float* __restrict__ ley, const float* __restrict__ eyep,
    const float* __restrict__ hscale, const float* __restrict__ hoff,
    const float* __restrict__ pJf, const float* __restrict__ tbj,
    const int* __restrict__ hidx, const int* __restrict__ s2f,
    float* __restrict__ new_t)
{
  int b = blockIdx.y;
  int i = blockIdx.x*256 + threadIdx.x;
  __shared__ float AL[60];
  __shared__ float mm[3];
  if (threadIdx.x < 60) AL[threadIdx.x] = Af[(size_t)b*60 + threadIdx.x];
  if (threadIdx.x < 3) {
    int c = threadIdx.x;
    float hm = 0.5f*(pJf[(size_t)b*15+9+c] + pJf[(size_t)b*15+12+c]);
    float tm = 0.5f*(tbj[(size_t)b*165 + 69 + c] + tbj[(size_t)b*165 + 72 + c]);
    mm[c] = tm - hm;
  }
  __syncthreads();
  if (i >= NHD) return;
  int v = hidx[i];
  float w[5];
  #pragma unroll
  for (int j=0;j<5;j++) w[j] = Wf[v*5+j];
  float T[12];
  #pragma unroll
  for (int e=0;e<12;e++){
    float s=0.f;
    #pragma unroll
    for (int j=0;j<5;j++) s += w[j]*AL[j*12+e];
    T[e]=s;
  }
  const float* vp = vpf + (size_t)b*NF3v + 3*v;
  float x0=vp[0], x1=vp[1], x2=vp[2];
  float el0 = eyep[b*2], el1 = eyep[b*2+1];
  float hs = hscale[b];
  int col = s2f[v];
  float* dst = new_t + (size_t)b*NS3v + 3*col;
  #pragma unroll
  for (int c=0;c<3;c++){
    float r = T[c*4]*x0 + T[c*4+1]*x1 + T[c*4+2]*x2 + T[c*4+3];
    r += rey[3*v+c]*el1 + ley[3*v+c]*el0;
    r = r*hs + hoff[b*3+c];
    dst[c] = r + mm[c];
  }
}

// ---------------- mano pose+skin + scatter into new_t ----------------------
__global__ __launch_bounds__(256) void k_mano_skin(
    const float* __restrict__ vshm, const float* __restrict__ pdirs,
    const float* __restrict__ pTl, const float* __restrict__ pTr,
    const float* __restrict__ Al, const float* __restrict__ Ar,
    const float* __restrict__ Wm, const float* __restrict__ Jm,
    const float* __restrict__ lsc, const float* __restrict__ loffp,
    const float* __restrict__ rsc, const float* __restrict__ roffp,
    const float* __restrict__ tbj,
    const int* __restrict__ s2ml, const int* __restrict__ s2mr,
    float* __restrict__ new_t)
{
  int hand = blockIdx.z;
  int b = blockIdx.y;
  int v = blockIdx.x*256 + threadIdx.x;
  const float* pT = hand? pTr : pTl;
  const float* A  = (hand? Ar : Al) + (size_t)b*192;
  __shared__ float AL[192];
  __shared__ float PF[KPM];
  if (threadIdx.x < 192) AL[threadIdx.x] = A[threadIdx.x];
  if (threadIdx.x >= 192 && threadIdx.x < 192+64) {
    for (int k = threadIdx.x - 192; k < KPM; k += 64) PF[k] = pT[k*NB + b];
  }
  __syncthreads();
  if (v >= VM) return;
  float vp0=vshm[3*v], vp1=vshm[3*v+1], vp2=vshm[3*v+2];
  for (int k=0;k<KPM;k++) {
    float p = PF[k];
    vp0 += p * pdirs[(size_t)k*NM3v + 3*v];
    vp1 += p * pdirs[(size_t)k*NM3v + 3*v+1];
    vp2 += p * pdirs[(size_t)k*NM3v + 3*v+2];
  }
  float T[12];
  #pragma unroll
  for (int e=0;e<12;e++) T[e]=0.f;
  for (int j=0;j<16;j++){
    float w = Wm[v*16+j];
    #pragma unroll
    for (int e=0;e<12;e++) T[e] += w*AL[j*12+e];
  }
  float sc = hand? rsc[b] : lsc[b];
  const float* of = hand? (roffp+b*3) : (loffp+b*3);
  const float* tb = tbj + (size_t)b*165 + (hand?21:20)*3;
  int col = (hand? s2mr : s2ml)[v];
  float* dst = new_t + (size_t)b*NS3v + 3*col;
  #pragma unroll
  for (int c=0;c<3;c++){
    float r = T[c*4]*vp0 + T[c*4+1]*vp1 + T[c*4+2]*vp2 + T[c*4+3];
    r = r*sc + of[c];
    r = r - Jm[c];
    if (hand==0 && c==0) r = -r;
    dst[c] = r + tb[c];
  }
}

// ---------------- final 55-joint skin --------------------------------------
// R7 fix: unroll 1 on jq kills LDS-load hoist (was VGPR=256 + 1.7 GB spill);
// 2 v/thread + SKV=128 -> LDS 41.5 KB (3 blocks/CU). 805 us -> off top-5.
#define SKV 128
__global__ __launch_bounds__(256) void k_skin(
    const float* __restrict__ W, const float* __restrict__ As,
    const float* __restrict__ vposed, float* __restrict__ outp)
{
  __shared__ __align__(16) float WL[SKV*60];   // 30720 B
  __shared__ __align__(16) float AL[4*672];    // 10752 B
  int tid = threadIdx.x;
  int v0 = blockIdx.x*SKV;
  int b0 = blockIdx.y*4;
  for (int i=tid; i<SKV*55; i+=256) {
    int vl = i/55, j = i%55;
    int v = v0+vl;
    WL[vl*60+j] = (v<VS)? W[(size_t)v*55+j] : 0.f;
  }
  for (int i=tid;i<SKV;i+=256) WL[i*60+55]=0.f;
  for (int i=tid; i<4*660; i+=256) {
    int bl = i/660, r = i%660;
    AL[bl*672 + r] = As[((size_t)(b0+bl))*660 + r];
  }
  if (tid < 48) {
    int bl=tid/12, e=tid%12;
    AL[bl*672 + 660 + e] = 0.f;
  }
  __syncthreads();
  int bl = tid>>6, lane = tid&63;
  int b = b0 + bl;
  const float* ALb = AL + bl*672;
  float T[2][12];
  #pragma unroll
  for (int q=0;q<2;q++)
    #pragma unroll
    for (int e=0;e<12;e++) T[q][e]=0.f;
  #pragma unroll 1
  for (int jq=0; jq<14; jq++) {
    float4 w40 = *(const float4*)&WL[lane*60 + jq*4];
    float4 w41 = *(const float4*)&WL[(lane+64)*60 + jq*4];
    #pragma unroll
    for (int jj=0;jj<4;jj++) {
      int j = jq*4+jj;
      float4 a0 = *(const float4*)&ALb[j*12];
      float4 a1 = *(const float4*)&ALb[j*12+4];
      float4 a2 = *(const float4*)&ALb[j*12+8];
      float w0 = (jj==0)?w40.x:(jj==1)?w40.y:(jj==2)?w40.z:w40.w;
      float w1 = (jj==0)?w41.x:(jj==1)?w41.y:(jj==2)?w41.z:w41.w;
      T[0][0]+=w0*a0.x; T[0][1]+=w0*a0.y; T[0][2] +=w0*a1.x; T[0][3] +=w0*a1.y;
      T[0][4]+=w0*a0.z; T[0][5]+=w0*a0.w; T[0][6] +=w0*a1.z; T[0][7] +=w0*a1.w;
      T[0][8]+=w0*a2.x; T[0][9]+=w0*a2.y; T[0][10]+=w0*a2.z; T[0][11]+=w0*a2.w;
      T[1][0]+=w1*a0.x; T[1][1]+=w1*a0.y; T[1][2] +=w1*a1.x; T[1][3] +=w1*a1.y;
      T[1][4]+=w1*a0.z; T[1][5]+=w1*a0.w; T[1][6] +=w1*a1.z; T[1][7] +=w1*a1.w;
      T[1][8]+=w1*a2.x; T[1][9]+=w1*a2.y; T[1][10]+=w1*a2.z; T[1][11]+=w1*a2.w;
    }
  }
  // T element mapping: [0]=A0,[1]=A1,[4]=A2,[5]=A3,[2]=A4,[3]=A5,[6]=A6,
  // [7]=A7,[8..11]=A8..A11 (un-permuted on apply below)
  #pragma unroll
  for (int q=0;q<2;q++) {
    int v = v0 + lane + 64*q;
    if (v < VS) {
      const float* vp = vposed + (size_t)b*NS3v + 3*v;
      float x0=vp[0], x1=vp[1], x2=vp[2];
      float* dst = outp + (size_t)b*NS3v + 3*v;
      dst[0] = T[q][0]*x0 + T[q][1]*x1 + T[q][4]*x2 + T[q][5];
      dst[1] = T[q][2]*x0 + T[q][3]*x1 + T[q][6]*x2 + T[q][7];
      dst[2] = T[q][8]*x0 + T[q][9]*x1 + T[q][10]*x2 + T[q][11];
    }
  }
}

extern "C" void kernel_launch(void* const* d_in, const int* in_sizes, int n_in,
                              void* d_out, int out_size, void* d_ws, size_t ws_size,
                              hipStream_t stream) {
  const float* sp   = (const float*)d_in[0];
  const float* fe   = (const float*)d_in[1];
  const float* eye  = (const float*)d_in[2];
  const float* jaw  = (const float*)d_in[3];
  const float* eyep = (const float*)d_in[4];
  const float* hsc  = (const float*)d_in[5];
  const float* hoff = (const float*)d_in[6];
  const float* lhp  = (const float*)d_in[7];
  const float* rhp  = (const float*)d_in[8];
  const float* lsc  = (const float*)d_in[9];
  const float* loff = (const float*)d_in[10];
  const float* rsc  = (const float*)d_in[11];
  const float* roff = (const float*)d_in[12];
  const float* be   = (const float*)d_in[13];
  const float* gp   = (const float*)d_in[14];
  const float* bp   = (const float*)d_in[15];
  const float* joff = (const float*)d_in[16];
  const float* mb   = (const float*)d_in[17];
  const float* f_tmpl = (const float*)d_in[18];
  const float* f_sd   = (const float*)d_in[19];
  const float* f_pd   = (const float*)d_in[20];
  const float* f_jr   = (const float*)d_in[21];
  const float* f_W    = (const float*)d_in[22];
  const float* rey    = (const float*)d_in[23];
  const float* ley    = (const float*)d_in[24];
  const float* m_tmpl = (const float*)d_in[25];
  const float* m_sd   = (const float*)d_in[26];
  const float* m_pd   = (const float*)d_in[27];
  const float* m_jr   = (const float*)d_in[28];
  const float* m_W    = (const float*)d_in[29];
  const float* s_tmpl = (const float*)d_in[30];
  const float* s_sd   = (const float*)d_in[31];
  const float* s_pd   = (const float*)d_in[32];
  const float* s_jr   = (const float*)d_in[33];
  const float* s_W    = (const float*)d_in[34];
  // setup_inputs() dict order (NOT reference-signature order!):
  //   35: smplx2flame_ind (VF), 36: smplx2mano_left (VM),
  //   37: smplx2mano_right (VM), 38: head_index (3000)
  const int* s2f  = (const int*)d_in[35];
  const int* s2ml = (const int*)d_in[36];
  const int* s2mr = (const int*)d_in[37];
  const int* hidx = (const int*)d_in[38];
  float* outp = (float*)d_out;

  // newt (v_template/v_posed) lives in d_out; k_skin reads/writes in-place.
  float* newt = outp;

  float* w = (float*)d_ws;
  size_t o = 0;
  auto A_ = [&](size_t n){ size_t r = o; o += (n + 3) & ~(size_t)3; return r; };
  float* bTf  = w + A_((size_t)KSH*NB);
  float* bTs  = w + A_((size_t)KSH*NB);
  float* pTf  = w + A_((size_t)KPF*NB);
  float* pTl  = w + A_((size_t)KPM*NB);
  float* pTr  = w + A_((size_t)KPM*NB);
  float* pTs  = w + A_((size_t)KPS*NB);
  float* rot  = w + A_((size_t)NB*92*9);
  float* vshf = w + A_((size_t)NB*NF3v);
  float* Jf   = w + A_((size_t)NB*15);
  float* pJf  = w + A_((size_t)NB*15);
  float* Af   = w + A_((size_t)NB*60);
  float* vshm = w + A_((size_t)NM3v);
  float* Jm   = w + A_((size_t)48);
  float* Al   = w + A_((size_t)NB*192);
  float* Ar   = w + A_((size_t)NB*192);
  float* tbj  = w + A_((size_t)NB*165);
  float* As   = w + A_((size_t)NB*660);
  float* partS = w + A_((size_t)NB*5*JSPLIT*33);
  float* partF = w + A_((size_t)NB*1*JSPLIT*33);
  (void)ws_size; (void)n_in; (void)in_sizes; (void)out_size;

  // 1. prep: transposes + rodrigues
  {
    int total = 2*KSH*NB + 92*NB;
    k_prep<<<(total+255)/256, 256, 0, stream>>>(sp, fe, be, eye, jaw, lhp, rhp, gp, bp,
                                                bTf, bTs, rot, pTf, pTl, pTr, pTs);
  }
  // 2. smplx shape GEMM -> new_t (in d_out)
  k_gemm_shaped<<<(NS3v+63)/64, 256, 0, stream>>>(s_sd, bTs, s_tmpl, newt, NS3v, KSH);
  // 3. smplx joint regression (+joints_offset) -> tbj  [split-V]
  k_jreg_part<<<dim3(NB,5,JSPLIT), 256, 0, stream>>>(s_jr, newt, partS, 55, VS, 11, 5);
  k_jreg_reduce<<<(NB*55*3+255)/256, 256, 0, stream>>>(partS, joff, tbj, 55, 11, 5);
  // 4. flame shape GEMM -> vshf
  k_gemm_shaped<<<(NF3v+63)/64, 256, 0, stream>>>(f_sd, bTf, f_tmpl, vshf, NF3v, KSH);
  // 5. flame joint regression -> Jf  [split-V]
  k_jreg_part<<<dim3(NB,1,JSPLIT), 256, 0, stream>>>(f_jr, vshf, partF, 5, VF, 5, 1);
  k_jreg_reduce<<<(NB*5*3+255)/256, 256, 0, stream>>>(partF, nullptr, Jf, 5, 5, 1);
  // 6. mano shape (batch independent) -> vshm, Jm  [R9: parallelized]
  k_mano_sh<<<(NM3v+255)/256, 256, 0, stream>>>(m_tmpl, m_sd, mb, vshm);
  k_mano_jreg<<<16, 256, 0, stream>>>(m_jr, vshm, Jm);
  // 7. FK all models -> Af, Al, Ar, As, pJf
  k_fk<<<dim3(NB,4), 64, 0, stream>>>(rot, Jf, Jm, tbj, Af, Al, Ar, As, pJf);
  // 8. flame pose GEMM in-place -> vshf becomes v_posed_f
  k_gemm_pose<<<(NF3v+63)/64, 256, 0, stream>>>(f_pd, pTf, vshf, NF3v, KPF);
  // 9. flame skin at head_index -> scatter into new_t
  k_head<<<dim3((NHD+255)/256, NB), 256, 0, stream>>>(vshf, Af, f_W, rey, ley, eyep,
                                                      hsc, hoff, pJf, tbj, hidx, s2f, newt);
  // 10. mano pose+skin both hands -> scatter into new_t
  k_mano_skin<<<dim3((VM+255)/256, NB, 2), 256, 0, stream>>>(vshm, m_pd, pTl, pTr, Al, Ar,
                                                             m_W, Jm, lsc, loff, rsc, roff,
                                                             tbj, s2ml, s2mr, newt);
  // 11. smplx pose GEMM in-place -> new_t becomes v_posed
  k_gemm_pose<<<(NS3v+63)/64, 256, 0, stream>>>(s_pd, pTs, newt, NS3v, KPS);
  // 12. final skin -> d_out (in-place over newt)
  k_skin<<<dim3((VS+SKV-1)/SKV, NB/4), 256, 0, stream>>>(s_W, As, newt, outp);
}